// Round 1
// baseline (880.732 us; speedup 1.0000x reference)
//
#include <hip/hip_runtime.h>
#include <hip/hip_fp16.h>
#include <math.h>

#define NNODE 50000
#define NEDGE 800000
#define FIN 128
#define EDIM 64
#define HC 256
#define NH 4
#define CC 64
#define SCAN_TILE 512
#define EB 128   // edges per block in k_elog_both

typedef _Float16 half8v __attribute__((ext_vector_type(8)));
typedef _Float16 half4v __attribute__((ext_vector_type(4)));
typedef float floatx4 __attribute__((ext_vector_type(4)));

// ---------------- CSR build (dst -> incoming edge list) ----------------
__global__ void k_count(const int* __restrict__ dst, int* counts, int E) {
    int e = blockIdx.x * 256 + threadIdx.x;
    if (e < E) atomicAdd(&counts[dst[e]], 1);
}

__global__ void k_scan1(const int* __restrict__ counts, int* offs, int* tilesums, int N) {
    __shared__ int s[SCAN_TILE];
    int t = threadIdx.x;
    int i = blockIdx.x * SCAN_TILE + t;
    int v = (i < N) ? counts[i] : 0;
    s[t] = v;
    for (int off = 1; off < SCAN_TILE; off <<= 1) {
        __syncthreads();
        int x = (t >= off) ? s[t - off] : 0;
        __syncthreads();
        s[t] += x;
    }
    __syncthreads();
    if (i < N) offs[i] = s[t] - v;  // exclusive within tile
    if (t == SCAN_TILE - 1) tilesums[blockIdx.x] = s[t];
}

// parallel scan over tile sums (nt <= 128); replaces serial 1-thread loop
__global__ void k_scan2(int* tilesums, int nt) {
    __shared__ int s[128];
    int t = threadIdx.x;
    int v = (t < nt) ? tilesums[t] : 0;
    s[t] = v;
    for (int off = 1; off < 128; off <<= 1) {
        __syncthreads();
        int x = (t >= off) ? s[t - off] : 0;
        __syncthreads();
        s[t] += x;
    }
    __syncthreads();
    if (t < nt) tilesums[t] = s[t] - v;  // exclusive
}

__global__ void k_scan3(int* offs, const int* __restrict__ tilesums, int N, int E) {
    int t = threadIdx.x;
    int i = blockIdx.x * SCAN_TILE + t;
    if (i < N) offs[i] += tilesums[blockIdx.x];
    if (i == 0) offs[N] = E;
}

// srcs[pos] = src[e] (CSR-ordered src ids); epos[e] = pos (edge -> CSR slot)
__global__ void k_fill(const int* __restrict__ src, const int* __restrict__ dst,
                       const int* __restrict__ offs, int* cursor,
                       int* __restrict__ srcs, int* __restrict__ epos, int E) {
    int e = blockIdx.x * 256 + threadIdx.x;
    if (e < E) {
        int d = dst[e];
        int pos = offs[d] + atomicAdd(&cursor[d], 1);
        srcs[pos] = src[e];
        epos[e] = pos;
    }
}

__device__ inline float4 h4_to_f4(uint2 r) {
    float2 fa = __half22float2(*(__half2*)&r.x);
    float2 fb = __half22float2(*(__half2*)&r.y);
    return make_float4(fa.x, fa.y, fb.x, fb.y);
}

__device__ inline float sel_h(float4 v, int head) {
    return head == 0 ? v.x : head == 1 ? v.y : head == 2 ? v.z : v.w;
}

// W[K,256] fp32 -> Wt[256,K] fp16 (transpose); grid=K, block=256
__global__ void k_castW(const float* __restrict__ W, _Float16* __restrict__ Wt, int K) {
    int k = blockIdx.x, n = threadIdx.x;
    Wt[(size_t)n * K + k] = (_Float16)W[(size_t)k * HC + n];
}

// ---------------- fp16 MFMA GEMM + fused avec epilogue ----------------
// H16[M,256] = A[M,K] @ Wt16^T ; asrc/adst[row,h] = sum_c h[row,h,c]*att[h,c]
// wave = 16 rows x 256 cols (16 acc tiles), block = 4 waves = 64 rows
template <typename AT>
__global__ __launch_bounds__(256) void k_gemm_mfma(const AT* __restrict__ A,
                                                   const _Float16* __restrict__ Wt16,
                                                   _Float16* __restrict__ H16,
                                                   const float* __restrict__ att_s,
                                                   const float* __restrict__ att_d,
                                                   float* __restrict__ asrc,
                                                   float* __restrict__ adst,
                                                   int M, int K) {
    int wave = threadIdx.x >> 6, lane = threadIdx.x & 63;
    int quad = lane >> 4, l16 = lane & 15;
    int row = blockIdx.x * 64 + wave * 16 + l16;     // A-frag row (m = lane&15)
    bool rok = row < M;
    floatx4 acc[16];
#pragma unroll
    for (int i = 0; i < 16; i++) acc[i] = (floatx4)(0.0f);
    int nk = K >> 5;
    for (int kk = 0; kk < nk; kk++) {
        half8v a = {};
        if (rok) {
            if constexpr (sizeof(AT) == 2) {
                a = *(const half8v*)(A + (size_t)row * K + kk * 32 + quad * 8);
            } else {
                const float* ap = (const float*)A + (size_t)row * K + kk * 32 + quad * 8;
                float4 v0 = *(const float4*)ap;
                float4 v1 = *(const float4*)(ap + 4);
                a[0] = (_Float16)v0.x; a[1] = (_Float16)v0.y;
                a[2] = (_Float16)v0.z; a[3] = (_Float16)v0.w;
                a[4] = (_Float16)v1.x; a[5] = (_Float16)v1.y;
                a[6] = (_Float16)v1.z; a[7] = (_Float16)v1.w;
            }
        }
#pragma unroll
        for (int nt = 0; nt < 16; nt++) {
            half8v b = *(const half8v*)(Wt16 + (size_t)(nt * 16 + l16) * K + kk * 32 + quad * 8);
            acc[nt] = __builtin_amdgcn_mfma_f32_16x16x32_f16(a, b, acc[nt], 0, 0, 0);
        }
    }
    // lane holds rows quad*4+r (r=0..3), cols nt*16+l16; head of col = nt>>2
    float asl[16], adl[16];
#pragma unroll
    for (int nt = 0; nt < 16; nt++) {
        asl[nt] = att_s[nt * 16 + l16];
        adl[nt] = att_d[nt * 16 + l16];
    }
    int orow0 = blockIdx.x * 64 + wave * 16 + quad * 4;
#pragma unroll
    for (int r = 0; r < 4; r++) {
        int orow = orow0 + r;
        float4 vs4, vd4;
        float* vsp = (float*)&vs4;
        float* vdp = (float*)&vd4;
#pragma unroll
        for (int hh = 0; hh < 4; hh++) {
            float vs = 0.f, vd = 0.f;
#pragma unroll
            for (int q = 0; q < 4; q++) {
                int nt = hh * 4 + q;
                float hv = acc[nt][r];
                vs += hv * asl[nt];
                vd += hv * adl[nt];
            }
            vs += __shfl_xor(vs, 1, 64); vd += __shfl_xor(vd, 1, 64);
            vs += __shfl_xor(vs, 2, 64); vd += __shfl_xor(vd, 2, 64);
            vs += __shfl_xor(vs, 4, 64); vd += __shfl_xor(vd, 4, 64);
            vs += __shfl_xor(vs, 8, 64); vd += __shfl_xor(vd, 8, 64);
            vsp[hh] = vs; vdp[hh] = vd;
        }
        if (l16 == 0 && orow < M) {
            ((float4*)asrc)[orow] = vs4;
            ((float4*)adst)[orow] = vd4;
        }
    }
#pragma unroll
    for (int r = 0; r < 4; r++) {
        int orow = orow0 + r;
        if (orow < M) {
#pragma unroll
            for (int nt = 0; nt < 16; nt++)
                H16[(size_t)orow * HC + nt * 16 + l16] = (_Float16)acc[nt][r];
        }
    }
}

// ---------------- we_att[d,h] = sum_c edgeW[d, h*64+c] * att_e[h,c] ----------------
__global__ void k_weatt(const float* __restrict__ edgeW, const float* __restrict__ att_e,
                        float* we) {
    int t = threadIdx.x;
    int d = t >> 2, hh = t & 3;
    float s = 0.f;
    for (int c = 0; c < 64; c++) s += edgeW[d * HC + hh * 64 + c] * att_e[hh * 64 + c];
    we[d * 4 + hh] = s;
}

// ---------------- elog{1,2}[pos(e),h] = edge_feat[e,:] . we{1,2}[:,h] ----------------
// Scattered to CSR order via epos so the aggregation reads elog sequentially.
__global__ __launch_bounds__(128) void k_elog_both(const float* __restrict__ ef,
                                                   const float* __restrict__ we1,
                                                   const float* __restrict__ we2,
                                                   const int* __restrict__ epos,
                                                   float* __restrict__ elogc1,
                                                   float* __restrict__ elogc2, int E) {
    __shared__ float sEf[EB][65];
    int t = threadIdx.x;
    int e0 = blockIdx.x * EB;
    for (int i = 0; i < 16; i++) {
        int q = t + i * 128;
        int le = q >> 4, c4 = (q & 15) << 2;
        int ge = e0 + le;
        float4 v = make_float4(0.f, 0.f, 0.f, 0.f);
        if (ge < E) v = *(const float4*)(ef + (size_t)ge * EDIM + c4);
        sEf[le][c4 + 0] = v.x; sEf[le][c4 + 1] = v.y;
        sEf[le][c4 + 2] = v.z; sEf[le][c4 + 3] = v.w;
    }
    __syncthreads();
    float a1[4] = {}, a2[4] = {};
#pragma unroll 8
    for (int c = 0; c < 64; c++) {
        float v = sEf[t][c];
        float4 w1 = *(const float4*)(we1 + c * 4);
        float4 w2 = *(const float4*)(we2 + c * 4);
        a1[0] += v * w1.x; a1[1] += v * w1.y; a1[2] += v * w1.z; a1[3] += v * w1.w;
        a2[0] += v * w2.x; a2[1] += v * w2.y; a2[2] += v * w2.z; a2[3] += v * w2.w;
    }
    int e = e0 + t;
    if (e < E) {
        int pos = epos[e];
        ((float4*)elogc1)[pos] = make_float4(a1[0], a1[1], a1[2], a1[3]);
        ((float4*)elogc2)[pos] = make_float4(a2[0], a2[1], a2[2], a2[3]);
    }
}

// ---------------- fully fused attention + aggregation ----------------
// wave/node; lane -> flat channel group (head = lane>>4). Single sweep over the
// node's CSR range: per-edge p computed inline (softmax is shift-free here),
// elog segment-sum accumulated per-lane for the self-loop mean. No pcsr/pself.
template <int LAYER>
__global__ __launch_bounds__(256) void k_aggr_fused(const _Float16* __restrict__ hb,
                                                    const float* __restrict__ elogc,
                                                    const float* __restrict__ asrc,
                                                    const float* __restrict__ adst,
                                                    const int* __restrict__ offs,
                                                    const int* __restrict__ srcs,
                                                    const float* __restrict__ bias,
                                                    _Float16* __restrict__ out16,
                                                    float* __restrict__ out32, int N) {
    int wave = threadIdx.x >> 6, lane = threadIdx.x & 63;
    int n = blockIdx.x * 4 + wave;
    if (n >= N) return;
    int head = lane >> 4;
    const uint2* hf = (const uint2*)hb;     // 4 halves per entry, 64 entries per row
    const float4* elc = (const float4*)elogc;
    const float4* asp = (const float4*)asrc;
    int beg = offs[n], end = offs[n + 1];

    float adnh = sel_h(((const float4*)adst)[n], head);
    float asnh = sel_h(asp[n], head);

    float denom = 0.f, selsum = 0.f;
    float ax = 0.f, ay = 0.f, az = 0.f, aw = 0.f;

    int i = beg;
    for (; i + 8 <= end; i += 8) {
        int s[8];
        uint2 r[8];
        float4 el[8];
        float4 a4[8];
#pragma unroll
        for (int j = 0; j < 8; j++) s[j] = srcs[i + j];
#pragma unroll
        for (int j = 0; j < 8; j++) r[j] = hf[(size_t)s[j] * 64 + lane];
#pragma unroll
        for (int j = 0; j < 8; j++) el[j] = elc[i + j];
#pragma unroll
        for (int j = 0; j < 8; j++) a4[j] = asp[s[j]];
#pragma unroll
        for (int j = 0; j < 8; j++) {
            float eh = sel_h(el[j], head);
            selsum += eh;
            float l = sel_h(a4[j], head) + adnh + eh;
            l = l > 0.f ? l : 0.2f * l;
            float w = expf(l);
            denom += w;
            float4 h4 = h4_to_f4(r[j]);
            ax += w * h4.x; ay += w * h4.y; az += w * h4.z; aw += w * h4.w;
        }
    }
    for (; i < end; i++) {
        int s0 = srcs[i];
        uint2 r0 = hf[(size_t)s0 * 64 + lane];
        float4 el0 = elc[i];
        float4 a40 = asp[s0];
        float eh = sel_h(el0, head);
        selsum += eh;
        float l = sel_h(a40, head) + adnh + eh;
        l = l > 0.f ? l : 0.2f * l;
        float w = expf(l);
        denom += w;
        float4 h4 = h4_to_f4(r0);
        ax += w * h4.x; ay += w * h4.y; az += w * h4.z; aw += w * h4.w;
    }

    // self-loop: attr = mean of incoming elog (every lane holds the full sum)
    float cnt = (float)(end - beg);
    if (cnt < 1.f) cnt = 1.f;
    float ls = asnh + adnh + selsum / cnt;
    ls = ls > 0.f ? ls : 0.2f * ls;
    float ws = expf(ls);
    denom += ws;
    float4 hn = h4_to_f4(hf[(size_t)n * 64 + lane]);
    ax += ws * hn.x; ay += ws * hn.y; az += ws * hn.z; aw += ws * hn.w;

    float inv = 1.0f / (denom + 1e-16f);
    ax *= inv; ay *= inv; az *= inv; aw *= inv;

    if (LAYER == 1) {
        float4 bv = ((const float4*)bias)[lane];
        half4v o;
        float v;
        v = ax + bv.x; o[0] = (_Float16)(v > 0.f ? v : expf(v) - 1.0f);
        v = ay + bv.y; o[1] = (_Float16)(v > 0.f ? v : expf(v) - 1.0f);
        v = az + bv.z; o[2] = (_Float16)(v > 0.f ? v : expf(v) - 1.0f);
        v = aw + bv.w; o[3] = (_Float16)(v > 0.f ? v : expf(v) - 1.0f);
        ((half4v*)(out16 + (size_t)n * HC))[lane] = o;
    } else {
        // mean over heads: reduce lanes {l, l^16, l^32, l^48}
        ax += __shfl_xor(ax, 16, 64); ax += __shfl_xor(ax, 32, 64);
        ay += __shfl_xor(ay, 16, 64); ay += __shfl_xor(ay, 32, 64);
        az += __shfl_xor(az, 16, 64); az += __shfl_xor(az, 32, 64);
        aw += __shfl_xor(aw, 16, 64); aw += __shfl_xor(aw, 32, 64);
        if (lane < 16) {
            float4 bv = ((const float4*)bias)[lane];
            float4 o;
            o.x = 0.25f * ax + bv.x;
            o.y = 0.25f * ay + bv.y;
            o.z = 0.25f * az + bv.z;
            o.w = 0.25f * aw + bv.w;
            ((float4*)(out32 + (size_t)n * CC))[lane] = o;
        }
    }
}

extern "C" void kernel_launch(void* const* d_in, const int* in_sizes, int n_in,
                              void* d_out, int out_size, void* d_ws, size_t ws_size,
                              hipStream_t stream) {
    const float* x   = (const float*)d_in[0];
    const float* ef  = (const float*)d_in[1];
    const int*   ei  = (const int*)d_in[2];
    const float* W1  = (const float*)d_in[3];
    const float* as1 = (const float*)d_in[4];
    const float* ad1 = (const float*)d_in[5];
    const float* ae1 = (const float*)d_in[6];
    const float* b1  = (const float*)d_in[7];
    const float* eW1 = (const float*)d_in[8];
    const float* W2  = (const float*)d_in[9];
    const float* as2 = (const float*)d_in[10];
    const float* ad2 = (const float*)d_in[11];
    const float* ae2 = (const float*)d_in[12];
    const float* b2  = (const float*)d_in[13];
    const float* eW2 = (const float*)d_in[14];
    float* out = (float*)d_out;
    const int* srcp = ei;
    const int* dstp = ei + NEDGE;

    char* w = (char*)d_ws;
    auto alloc = [&](size_t bytes) -> char* {
        char* r = w;
        w += (bytes + 255) / 256 * 256;
        return r;
    };
    _Float16* hb16  = (_Float16*)alloc((size_t)NNODE * HC * 2);   // h (fp16, both layers)
    _Float16* x216  = (_Float16*)alloc((size_t)NNODE * HC * 2);   // layer-2 GEMM input
    _Float16* wt1   = (_Float16*)alloc((size_t)HC * FIN * 2);     // W1^T fp16
    _Float16* wt2   = (_Float16*)alloc((size_t)HC * HC * 2);      // W2^T fp16
    float* elogc1 = (float*)alloc((size_t)NEDGE * 4 * 4);         // CSR-ordered
    float* elogc2 = (float*)alloc((size_t)NEDGE * 4 * 4);         // CSR-ordered
    float* asrc   = (float*)alloc((size_t)NNODE * 4 * 4);
    float* adst   = (float*)alloc((size_t)NNODE * 4 * 4);
    float* webuf1 = (float*)alloc(64 * 4 * 4);
    float* webuf2 = (float*)alloc(64 * 4 * 4);
    int* counts  = (int*)alloc((size_t)NNODE * 4);
    int* offs    = (int*)alloc((size_t)(NNODE + 1) * 4);
    int* tiles   = (int*)alloc(1024 * 4);
    int* cursor  = (int*)alloc((size_t)NNODE * 4);
    int* srcs    = (int*)alloc((size_t)NEDGE * 4);                // CSR-ordered src ids
    int* epos    = (int*)alloc((size_t)NEDGE * 4);                // edge -> CSR slot

    hipMemsetAsync(counts, 0, (size_t)NNODE * 4, stream);
    hipMemsetAsync(cursor, 0, (size_t)NNODE * 4, stream);

    // CSR build (shared by both layers)
    k_count<<<(NEDGE + 255) / 256, 256, 0, stream>>>(dstp, counts, NEDGE);
    int nt = (NNODE + SCAN_TILE - 1) / SCAN_TILE;
    k_scan1<<<nt, SCAN_TILE, 0, stream>>>(counts, offs, tiles, NNODE);
    k_scan2<<<1, 128, 0, stream>>>(tiles, nt);
    k_scan3<<<nt, SCAN_TILE, 0, stream>>>(offs, tiles, NNODE, NEDGE);
    k_fill<<<(NEDGE + 255) / 256, 256, 0, stream>>>(srcp, dstp, offs, cursor, srcs, epos, NEDGE);

    // fp16 weight transposes
    k_castW<<<FIN, 256, 0, stream>>>(W1, wt1, FIN);
    k_castW<<<HC, 256, 0, stream>>>(W2, wt2, HC);

    // edge logits for BOTH layers in one pass over ef, scattered to CSR order
    k_weatt<<<1, 256, 0, stream>>>(eW1, ae1, webuf1);
    k_weatt<<<1, 256, 0, stream>>>(eW2, ae2, webuf2);
    k_elog_both<<<(NEDGE + EB - 1) / EB, EB, 0, stream>>>(ef, webuf1, webuf2, epos, elogc1, elogc2, NEDGE);

    // ---- layer 1 ----
    k_gemm_mfma<float><<<(NNODE + 63) / 64, 256, 0, stream>>>(x, wt1, hb16, as1, ad1, asrc, adst, NNODE, FIN);
    k_aggr_fused<1><<<(NNODE + 3) / 4, 256, 0, stream>>>(hb16, elogc1, asrc, adst, offs, srcs, b1, x216, nullptr, NNODE);

    // ---- layer 2 ----
    k_gemm_mfma<_Float16><<<(NNODE + 63) / 64, 256, 0, stream>>>(x216, wt2, hb16, as2, ad2, asrc, adst, NNODE, HC);
    k_aggr_fused<2><<<(NNODE + 3) / 4, 256, 0, stream>>>(hb16, elogc2, asrc, adst, offs, srcs, b2, nullptr, out, NNODE);
}

// Round 2
// 724.797 us; speedup vs baseline: 1.2151x; 1.2151x over previous
//
#include <hip/hip_runtime.h>
#include <hip/hip_fp16.h>
#include <math.h>

#define NNODE 50000
#define NEDGE 800000
#define FIN 128
#define EDIM 64
#define HC 256
#define NH 4
#define CC 64
#define SCAN_TILE 512
#define EB 128   // edges per block in k_elog_both

typedef _Float16 half8v __attribute__((ext_vector_type(8)));
typedef _Float16 half4v __attribute__((ext_vector_type(4)));
typedef float floatx4 __attribute__((ext_vector_type(4)));

// ---------------- CSR build (dst -> incoming edge list) ----------------
__global__ void k_count(const int* __restrict__ dst, int* counts, int E) {
    int e = blockIdx.x * 256 + threadIdx.x;
    if (e < E) atomicAdd(&counts[dst[e]], 1);
}

__global__ void k_scan1(const int* __restrict__ counts, int* offs, int* tilesums, int N) {
    __shared__ int s[SCAN_TILE];
    int t = threadIdx.x;
    int i = blockIdx.x * SCAN_TILE + t;
    int v = (i < N) ? counts[i] : 0;
    s[t] = v;
    for (int off = 1; off < SCAN_TILE; off <<= 1) {
        __syncthreads();
        int x = (t >= off) ? s[t - off] : 0;
        __syncthreads();
        s[t] += x;
    }
    __syncthreads();
    if (i < N) offs[i] = s[t] - v;  // exclusive within tile
    if (t == SCAN_TILE - 1) tilesums[blockIdx.x] = s[t];
}

// parallel scan over tile sums (nt <= 128)
__global__ void k_scan2(int* tilesums, int nt) {
    __shared__ int s[128];
    int t = threadIdx.x;
    int v = (t < nt) ? tilesums[t] : 0;
    s[t] = v;
    for (int off = 1; off < 128; off <<= 1) {
        __syncthreads();
        int x = (t >= off) ? s[t - off] : 0;
        __syncthreads();
        s[t] += x;
    }
    __syncthreads();
    if (t < nt) tilesums[t] = s[t] - v;  // exclusive
}

__global__ void k_scan3(int* offs, const int* __restrict__ tilesums, int N, int E) {
    int t = threadIdx.x;
    int i = blockIdx.x * SCAN_TILE + t;
    if (i < N) offs[i] += tilesums[blockIdx.x];
    if (i == 0) offs[N] = E;
}

// srcs[pos] = src[e] (CSR-ordered src ids); epos[e] = pos (edge -> CSR slot)
__global__ void k_fill(const int* __restrict__ src, const int* __restrict__ dst,
                       const int* __restrict__ offs, int* cursor,
                       int* __restrict__ srcs, int* __restrict__ epos, int E) {
    int e = blockIdx.x * 256 + threadIdx.x;
    if (e < E) {
        int d = dst[e];
        int pos = offs[d] + atomicAdd(&cursor[d], 1);
        srcs[pos] = src[e];
        epos[e] = pos;
    }
}

__device__ inline float4 h4_to_f4(uint2 r) {
    float2 fa = __half22float2(*(__half2*)&r.x);
    float2 fb = __half22float2(*(__half2*)&r.y);
    return make_float4(fa.x, fa.y, fb.x, fb.y);
}

__device__ inline float sel_h(float4 v, int head) {
    return head == 0 ? v.x : head == 1 ? v.y : head == 2 ? v.z : v.w;
}

// W[K,256] fp32 -> Wt[256,K] fp16 (transpose); grid=K, block=256
__global__ void k_castW(const float* __restrict__ W, _Float16* __restrict__ Wt, int K) {
    int k = blockIdx.x, n = threadIdx.x;
    Wt[(size_t)n * K + k] = (_Float16)W[(size_t)k * HC + n];
}

// ---------------- fp16 MFMA GEMM + fused avec epilogue ----------------
template <typename AT>
__global__ __launch_bounds__(256) void k_gemm_mfma(const AT* __restrict__ A,
                                                   const _Float16* __restrict__ Wt16,
                                                   _Float16* __restrict__ H16,
                                                   const float* __restrict__ att_s,
                                                   const float* __restrict__ att_d,
                                                   float* __restrict__ asrc,
                                                   float* __restrict__ adst,
                                                   int M, int K) {
    int wave = threadIdx.x >> 6, lane = threadIdx.x & 63;
    int quad = lane >> 4, l16 = lane & 15;
    int row = blockIdx.x * 64 + wave * 16 + l16;     // A-frag row (m = lane&15)
    bool rok = row < M;
    floatx4 acc[16];
#pragma unroll
    for (int i = 0; i < 16; i++) acc[i] = (floatx4)(0.0f);
    int nk = K >> 5;
    for (int kk = 0; kk < nk; kk++) {
        half8v a = {};
        if (rok) {
            if constexpr (sizeof(AT) == 2) {
                a = *(const half8v*)(A + (size_t)row * K + kk * 32 + quad * 8);
            } else {
                const float* ap = (const float*)A + (size_t)row * K + kk * 32 + quad * 8;
                float4 v0 = *(const float4*)ap;
                float4 v1 = *(const float4*)(ap + 4);
                a[0] = (_Float16)v0.x; a[1] = (_Float16)v0.y;
                a[2] = (_Float16)v0.z; a[3] = (_Float16)v0.w;
                a[4] = (_Float16)v1.x; a[5] = (_Float16)v1.y;
                a[6] = (_Float16)v1.z; a[7] = (_Float16)v1.w;
            }
        }
#pragma unroll
        for (int nt = 0; nt < 16; nt++) {
            half8v b = *(const half8v*)(Wt16 + (size_t)(nt * 16 + l16) * K + kk * 32 + quad * 8);
            acc[nt] = __builtin_amdgcn_mfma_f32_16x16x32_f16(a, b, acc[nt], 0, 0, 0);
        }
    }
    // lane holds rows quad*4+r (r=0..3), cols nt*16+l16; head of col = nt>>2
    float asl[16], adl[16];
#pragma unroll
    for (int nt = 0; nt < 16; nt++) {
        asl[nt] = att_s[nt * 16 + l16];
        adl[nt] = att_d[nt * 16 + l16];
    }
    int orow0 = blockIdx.x * 64 + wave * 16 + quad * 4;
#pragma unroll
    for (int r = 0; r < 4; r++) {
        int orow = orow0 + r;
        float4 vs4, vd4;
        float* vsp = (float*)&vs4;
        float* vdp = (float*)&vd4;
#pragma unroll
        for (int hh = 0; hh < 4; hh++) {
            float vs = 0.f, vd = 0.f;
#pragma unroll
            for (int q = 0; q < 4; q++) {
                int nt = hh * 4 + q;
                float hv = acc[nt][r];
                vs += hv * asl[nt];
                vd += hv * adl[nt];
            }
            vs += __shfl_xor(vs, 1, 64); vd += __shfl_xor(vd, 1, 64);
            vs += __shfl_xor(vs, 2, 64); vd += __shfl_xor(vd, 2, 64);
            vs += __shfl_xor(vs, 4, 64); vd += __shfl_xor(vd, 4, 64);
            vs += __shfl_xor(vs, 8, 64); vd += __shfl_xor(vd, 8, 64);
            vsp[hh] = vs; vdp[hh] = vd;
        }
        if (l16 == 0 && orow < M) {
            ((float4*)asrc)[orow] = vs4;
            ((float4*)adst)[orow] = vd4;
        }
    }
#pragma unroll
    for (int r = 0; r < 4; r++) {
        int orow = orow0 + r;
        if (orow < M) {
#pragma unroll
            for (int nt = 0; nt < 16; nt++)
                H16[(size_t)orow * HC + nt * 16 + l16] = (_Float16)acc[nt][r];
        }
    }
}

// ---------------- we_att[d,h] = sum_c edgeW[d, h*64+c] * att_e[h,c] ----------------
__global__ void k_weatt(const float* __restrict__ edgeW, const float* __restrict__ att_e,
                        float* we) {
    int t = threadIdx.x;
    int d = t >> 2, hh = t & 3;
    float s = 0.f;
    for (int c = 0; c < 64; c++) s += edgeW[d * HC + hh * 64 + c] * att_e[hh * 64 + c];
    we[d * 4 + hh] = s;
}

// ---------------- elog{1,2}[pos(e),h] = edge_feat[e,:] . we{1,2}[:,h] ----------------
__global__ __launch_bounds__(128) void k_elog_both(const float* __restrict__ ef,
                                                   const float* __restrict__ we1,
                                                   const float* __restrict__ we2,
                                                   const int* __restrict__ epos,
                                                   float* __restrict__ elogc1,
                                                   float* __restrict__ elogc2, int E) {
    __shared__ float sEf[EB][65];
    int t = threadIdx.x;
    int e0 = blockIdx.x * EB;
    for (int i = 0; i < 16; i++) {
        int q = t + i * 128;
        int le = q >> 4, c4 = (q & 15) << 2;
        int ge = e0 + le;
        float4 v = make_float4(0.f, 0.f, 0.f, 0.f);
        if (ge < E) v = *(const float4*)(ef + (size_t)ge * EDIM + c4);
        sEf[le][c4 + 0] = v.x; sEf[le][c4 + 1] = v.y;
        sEf[le][c4 + 2] = v.z; sEf[le][c4 + 3] = v.w;
    }
    __syncthreads();
    float a1[4] = {}, a2[4] = {};
#pragma unroll 8
    for (int c = 0; c < 64; c++) {
        float v = sEf[t][c];
        float4 w1 = *(const float4*)(we1 + c * 4);
        float4 w2 = *(const float4*)(we2 + c * 4);
        a1[0] += v * w1.x; a1[1] += v * w1.y; a1[2] += v * w1.z; a1[3] += v * w1.w;
        a2[0] += v * w2.x; a2[1] += v * w2.y; a2[2] += v * w2.z; a2[3] += v * w2.w;
    }
    int e = e0 + t;
    if (e < E) {
        int pos = epos[e];
        ((float4*)elogc1)[pos] = make_float4(a1[0], a1[1], a1[2], a1[3]);
        ((float4*)elogc2)[pos] = make_float4(a2[0], a2[1], a2[2], a2[3]);
    }
}

// ---------------- fused attention + aggregation, wave-cooperative ----------------
// wave per node. Per 64-edge chunk:
//  Phase A (edge-parallel): lane j loads srcs/elog/asrc of edge j (COALESCED),
//    computes all-4-head weights with __expf (4 exp per edge TOTAL), stores w4
//    to wave-private LDS; src id stays in a register.
//  Phase B (channel-parallel): per edge, readlane broadcasts src id to SGPR
//    (h-gather becomes saddr + constant lane voffset -> zero VALU addr math),
//    weight comes from a conflict-free LDS broadcast read.
template <int LAYER>
__global__ __launch_bounds__(256) void k_aggr_fused(const _Float16* __restrict__ hb,
                                                    const float* __restrict__ elogc,
                                                    const float* __restrict__ asrc,
                                                    const float* __restrict__ adst,
                                                    const int* __restrict__ offs,
                                                    const int* __restrict__ srcs,
                                                    const float* __restrict__ bias,
                                                    _Float16* __restrict__ out16,
                                                    float* __restrict__ out32, int N) {
    __shared__ float sW[4][256];   // [wave][edge*4+head]
    int wave = threadIdx.x >> 6, lane = threadIdx.x & 63;
    int n = blockIdx.x * 4 + wave;
    if (n >= N) return;
    int head = lane >> 4;
    const uint2* hf = (const uint2*)hb;     // 4 halves per entry, 64 entries per row
    const float4* elc = (const float4*)elogc;
    const float4* asp = (const float4*)asrc;
    float* sWp = sW[wave];
    int beg = offs[n], end = offs[n + 1];

    float4 adn = ((const float4*)adst)[n];
    float adnh = sel_h(adn, head);

    float denom = 0.f;
    float sx = 0.f, sy = 0.f, sz = 0.f, sw = 0.f;  // raw elog sums (all heads)
    float ax = 0.f, ay = 0.f, az = 0.f, aw = 0.f;

    for (int i0 = beg; i0 < end; i0 += 64) {
        int m = end - i0; if (m > 64) m = 64;
        bool act = lane < m;
        int sj = 0;
        float4 el = make_float4(0.f, 0.f, 0.f, 0.f);
        float4 a4 = make_float4(0.f, 0.f, 0.f, 0.f);
        if (act) {
            uint idx = (uint)(i0 + lane);
            sj = srcs[idx];
            el = elc[idx];
            a4 = asp[(uint)sj];
        }
        sx += el.x; sy += el.y; sz += el.z; sw += el.w;
        float4 w4;
        float l;
        l = a4.x + adn.x + el.x; l = l > 0.f ? l : 0.2f * l; w4.x = act ? __expf(l) : 0.f;
        l = a4.y + adn.y + el.y; l = l > 0.f ? l : 0.2f * l; w4.y = act ? __expf(l) : 0.f;
        l = a4.z + adn.z + el.z; l = l > 0.f ? l : 0.2f * l; w4.z = act ? __expf(l) : 0.f;
        l = a4.w + adn.w + el.w; l = l > 0.f ? l : 0.2f * l; w4.w = act ? __expf(l) : 0.f;
        *(float4*)&sWp[lane << 2] = w4;
        __builtin_amdgcn_wave_barrier();   // wave-private LDS; DS pipe is in-order per wave

        int j = 0;
        for (; j + 8 <= m; j += 8) {
            uint2 r[8];
            float w[8];
#pragma unroll
            for (int k = 0; k < 8; k++) {
                int sk = __builtin_amdgcn_readlane(sj, j + k);   // SGPR broadcast
                w[k] = sWp[((j + k) << 2) + head];
                r[k] = hf[(size_t)((uint)sk * 64u) + lane];
            }
#pragma unroll
            for (int k = 0; k < 8; k++) {
                float4 h4 = h4_to_f4(r[k]);
                denom += w[k];
                ax += w[k] * h4.x; ay += w[k] * h4.y;
                az += w[k] * h4.z; aw += w[k] * h4.w;
            }
        }
        for (; j < m; j++) {
            int sk = __builtin_amdgcn_readlane(sj, j);
            float wk = sWp[(j << 2) + head];
            uint2 rk = hf[(size_t)((uint)sk * 64u) + lane];
            float4 h4 = h4_to_f4(rk);
            denom += wk;
            ax += wk * h4.x; ay += wk * h4.y;
            az += wk * h4.z; aw += wk * h4.w;
        }
        __builtin_amdgcn_wave_barrier();   // before next chunk overwrites sW
    }

    // all-head elog totals (butterfly over 64 lanes), then pick own head
#pragma unroll
    for (int msk = 32; msk >= 1; msk >>= 1) {
        sx += __shfl_xor(sx, msk, 64);
        sy += __shfl_xor(sy, msk, 64);
        sz += __shfl_xor(sz, msk, 64);
        sw += __shfl_xor(sw, msk, 64);
    }
    float selh = sel_h(make_float4(sx, sy, sz, sw), head);

    // self-loop: attr = mean of incoming elog
    float cnt = (float)(end - beg);
    if (cnt < 1.f) cnt = 1.f;
    float asnh = sel_h(asp[(uint)n], head);
    float ls = asnh + adnh + selh / cnt;
    ls = ls > 0.f ? ls : 0.2f * ls;
    float ws = __expf(ls);
    denom += ws;
    float4 hn = h4_to_f4(hf[(size_t)n * 64 + lane]);
    ax += ws * hn.x; ay += ws * hn.y; az += ws * hn.z; aw += ws * hn.w;

    float inv = 1.0f / (denom + 1e-16f);
    ax *= inv; ay *= inv; az *= inv; aw *= inv;

    if (LAYER == 1) {
        float4 bv = ((const float4*)bias)[lane];
        half4v o;
        float v;
        v = ax + bv.x; o[0] = (_Float16)(v > 0.f ? v : __expf(v) - 1.0f);
        v = ay + bv.y; o[1] = (_Float16)(v > 0.f ? v : __expf(v) - 1.0f);
        v = az + bv.z; o[2] = (_Float16)(v > 0.f ? v : __expf(v) - 1.0f);
        v = aw + bv.w; o[3] = (_Float16)(v > 0.f ? v : __expf(v) - 1.0f);
        ((half4v*)(out16 + (size_t)n * HC))[lane] = o;
    } else {
        // mean over heads: reduce lanes {l, l^16, l^32, l^48}
        ax += __shfl_xor(ax, 16, 64); ax += __shfl_xor(ax, 32, 64);
        ay += __shfl_xor(ay, 16, 64); ay += __shfl_xor(ay, 32, 64);
        az += __shfl_xor(az, 16, 64); az += __shfl_xor(az, 32, 64);
        aw += __shfl_xor(aw, 16, 64); aw += __shfl_xor(aw, 32, 64);
        if (lane < 16) {
            float4 bv = ((const float4*)bias)[lane];
            float4 o;
            o.x = 0.25f * ax + bv.x;
            o.y = 0.25f * ay + bv.y;
            o.z = 0.25f * az + bv.z;
            o.w = 0.25f * aw + bv.w;
            ((float4*)(out32 + (size_t)n * CC))[lane] = o;
        }
    }
}

extern "C" void kernel_launch(void* const* d_in, const int* in_sizes, int n_in,
                              void* d_out, int out_size, void* d_ws, size_t ws_size,
                              hipStream_t stream) {
    const float* x   = (const float*)d_in[0];
    const float* ef  = (const float*)d_in[1];
    const int*   ei  = (const int*)d_in[2];
    const float* W1  = (const float*)d_in[3];
    const float* as1 = (const float*)d_in[4];
    const float* ad1 = (const float*)d_in[5];
    const float* ae1 = (const float*)d_in[6];
    const float* b1  = (const float*)d_in[7];
    const float* eW1 = (const float*)d_in[8];
    const float* W2  = (const float*)d_in[9];
    const float* as2 = (const float*)d_in[10];
    const float* ad2 = (const float*)d_in[11];
    const float* ae2 = (const float*)d_in[12];
    const float* b2  = (const float*)d_in[13];
    const float* eW2 = (const float*)d_in[14];
    float* out = (float*)d_out;
    const int* srcp = ei;
    const int* dstp = ei + NEDGE;

    char* w = (char*)d_ws;
    auto alloc = [&](size_t bytes) -> char* {
        char* r = w;
        w += (bytes + 255) / 256 * 256;
        return r;
    };
    _Float16* hb16  = (_Float16*)alloc((size_t)NNODE * HC * 2);   // h (fp16, both layers)
    _Float16* x216  = (_Float16*)alloc((size_t)NNODE * HC * 2);   // layer-2 GEMM input
    _Float16* wt1   = (_Float16*)alloc((size_t)HC * FIN * 2);     // W1^T fp16
    _Float16* wt2   = (_Float16*)alloc((size_t)HC * HC * 2);      // W2^T fp16
    float* elogc1 = (float*)alloc((size_t)NEDGE * 4 * 4);         // CSR-ordered
    float* elogc2 = (float*)alloc((size_t)NEDGE * 4 * 4);         // CSR-ordered
    float* asrc   = (float*)alloc((size_t)NNODE * 4 * 4);
    float* adst   = (float*)alloc((size_t)NNODE * 4 * 4);
    float* webuf1 = (float*)alloc(64 * 4 * 4);
    float* webuf2 = (float*)alloc(64 * 4 * 4);
    int* counts  = (int*)alloc((size_t)NNODE * 4);
    int* offs    = (int*)alloc((size_t)(NNODE + 1) * 4);
    int* tiles   = (int*)alloc(1024 * 4);
    int* cursor  = (int*)alloc((size_t)NNODE * 4);
    int* srcs    = (int*)alloc((size_t)NEDGE * 4);                // CSR-ordered src ids
    int* epos    = (int*)alloc((size_t)NEDGE * 4);                // edge -> CSR slot

    hipMemsetAsync(counts, 0, (size_t)NNODE * 4, stream);
    hipMemsetAsync(cursor, 0, (size_t)NNODE * 4, stream);

    // CSR build (shared by both layers)
    k_count<<<(NEDGE + 255) / 256, 256, 0, stream>>>(dstp, counts, NEDGE);
    int nt = (NNODE + SCAN_TILE - 1) / SCAN_TILE;
    k_scan1<<<nt, SCAN_TILE, 0, stream>>>(counts, offs, tiles, NNODE);
    k_scan2<<<1, 128, 0, stream>>>(tiles, nt);
    k_scan3<<<nt, SCAN_TILE, 0, stream>>>(offs, tiles, NNODE, NEDGE);
    k_fill<<<(NEDGE + 255) / 256, 256, 0, stream>>>(srcp, dstp, offs, cursor, srcs, epos, NEDGE);

    // fp16 weight transposes
    k_castW<<<FIN, 256, 0, stream>>>(W1, wt1, FIN);
    k_castW<<<HC, 256, 0, stream>>>(W2, wt2, HC);

    // edge logits for BOTH layers in one pass over ef, scattered to CSR order
    k_weatt<<<1, 256, 0, stream>>>(eW1, ae1, webuf1);
    k_weatt<<<1, 256, 0, stream>>>(eW2, ae2, webuf2);
    k_elog_both<<<(NEDGE + EB - 1) / EB, EB, 0, stream>>>(ef, webuf1, webuf2, epos, elogc1, elogc2, NEDGE);

    // ---- layer 1 ----
    k_gemm_mfma<float><<<(NNODE + 63) / 64, 256, 0, stream>>>(x, wt1, hb16, as1, ad1, asrc, adst, NNODE, FIN);
    k_aggr_fused<1><<<(NNODE + 3) / 4, 256, 0, stream>>>(hb16, elogc1, asrc, adst, offs, srcs, b1, x216, nullptr, NNODE);

    // ---- layer 2 ----
    k_gemm_mfma<_Float16><<<(NNODE + 63) / 64, 256, 0, stream>>>(x216, wt2, hb16, as2, ad2, asrc, adst, NNODE, HC);
    k_aggr_fused<2><<<(NNODE + 3) / 4, 256, 0, stream>>>(hb16, elogc2, asrc, adst, offs, srcs, b2, nullptr, out, NNODE);
}

// Round 3
// 711.337 us; speedup vs baseline: 1.2381x; 1.0189x over previous
//
#include <hip/hip_runtime.h>
#include <hip/hip_fp16.h>
#include <math.h>

#define NNODE 50000
#define NEDGE 800000
#define FIN 128
#define EDIM 64
#define HC 256
#define NH 4
#define CC 64
#define SCAN_TILE 512

typedef _Float16 half8v __attribute__((ext_vector_type(8)));
typedef _Float16 half4v __attribute__((ext_vector_type(4)));
typedef float floatx4 __attribute__((ext_vector_type(4)));

// ---------------- CSR build (dst -> incoming edge list) ----------------
__global__ void k_count(const int* __restrict__ dst, int* counts, int E) {
    int e = blockIdx.x * 256 + threadIdx.x;
    if (e < E) atomicAdd(&counts[dst[e]], 1);
}

__global__ void k_scan1(const int* __restrict__ counts, int* offs, int* tilesums, int N) {
    __shared__ int s[SCAN_TILE];
    int t = threadIdx.x;
    int i = blockIdx.x * SCAN_TILE + t;
    int v = (i < N) ? counts[i] : 0;
    s[t] = v;
    for (int off = 1; off < SCAN_TILE; off <<= 1) {
        __syncthreads();
        int x = (t >= off) ? s[t - off] : 0;
        __syncthreads();
        s[t] += x;
    }
    __syncthreads();
    if (i < N) offs[i] = s[t] - v;  // exclusive within tile
    if (t == SCAN_TILE - 1) tilesums[blockIdx.x] = s[t];
}

// parallel scan over tile sums (nt <= 128)
__global__ void k_scan2(int* tilesums, int nt) {
    __shared__ int s[128];
    int t = threadIdx.x;
    int v = (t < nt) ? tilesums[t] : 0;
    s[t] = v;
    for (int off = 1; off < 128; off <<= 1) {
        __syncthreads();
        int x = (t >= off) ? s[t - off] : 0;
        __syncthreads();
        s[t] += x;
    }
    __syncthreads();
    if (t < nt) tilesums[t] = s[t] - v;  // exclusive
}

__global__ void k_scan3(int* offs, const int* __restrict__ tilesums, int N, int E) {
    int t = threadIdx.x;
    int i = blockIdx.x * SCAN_TILE + t;
    if (i < N) offs[i] += tilesums[blockIdx.x];
    if (i == 0) offs[N] = E;
}

// srcs[pos] = src[e] (CSR-ordered src ids); epos[e] = pos (edge -> CSR slot)
__global__ void k_fill(const int* __restrict__ src, const int* __restrict__ dst,
                       const int* __restrict__ offs, int* cursor,
                       int* __restrict__ srcs, int* __restrict__ epos, int E) {
    int e = blockIdx.x * 256 + threadIdx.x;
    if (e < E) {
        int d = dst[e];
        int pos = offs[d] + atomicAdd(&cursor[d], 1);
        srcs[pos] = src[e];
        epos[e] = pos;
    }
}

__device__ inline float4 h4_to_f4(uint2 r) {
    float2 fa = __half22float2(*(__half2*)&r.x);
    float2 fb = __half22float2(*(__half2*)&r.y);
    return make_float4(fa.x, fa.y, fb.x, fb.y);
}

__device__ inline float sel_h(float4 v, int head) {
    return head == 0 ? v.x : head == 1 ? v.y : head == 2 ? v.z : v.w;
}

// W[K,256] fp32 -> Wt[256,K] fp16 (transpose); grid=K, block=256
__global__ void k_castW(const float* __restrict__ W, _Float16* __restrict__ Wt, int K) {
    int k = blockIdx.x, n = threadIdx.x;
    Wt[(size_t)n * K + k] = (_Float16)W[(size_t)k * HC + n];
}

// ---------------- fp16 MFMA GEMM + fused avec epilogue ----------------
template <typename AT>
__global__ __launch_bounds__(256) void k_gemm_mfma(const AT* __restrict__ A,
                                                   const _Float16* __restrict__ Wt16,
                                                   _Float16* __restrict__ H16,
                                                   const float* __restrict__ att_s,
                                                   const float* __restrict__ att_d,
                                                   float* __restrict__ asrc,
                                                   float* __restrict__ adst,
                                                   int M, int K) {
    int wave = threadIdx.x >> 6, lane = threadIdx.x & 63;
    int quad = lane >> 4, l16 = lane & 15;
    int row = blockIdx.x * 64 + wave * 16 + l16;     // A-frag row (m = lane&15)
    bool rok = row < M;
    floatx4 acc[16];
#pragma unroll
    for (int i = 0; i < 16; i++) acc[i] = (floatx4)(0.0f);
    int nk = K >> 5;
    for (int kk = 0; kk < nk; kk++) {
        half8v a = {};
        if (rok) {
            if constexpr (sizeof(AT) == 2) {
                a = *(const half8v*)(A + (size_t)row * K + kk * 32 + quad * 8);
            } else {
                const float* ap = (const float*)A + (size_t)row * K + kk * 32 + quad * 8;
                float4 v0 = *(const float4*)ap;
                float4 v1 = *(const float4*)(ap + 4);
                a[0] = (_Float16)v0.x; a[1] = (_Float16)v0.y;
                a[2] = (_Float16)v0.z; a[3] = (_Float16)v0.w;
                a[4] = (_Float16)v1.x; a[5] = (_Float16)v1.y;
                a[6] = (_Float16)v1.z; a[7] = (_Float16)v1.w;
            }
        }
#pragma unroll
        for (int nt = 0; nt < 16; nt++) {
            half8v b = *(const half8v*)(Wt16 + (size_t)(nt * 16 + l16) * K + kk * 32 + quad * 8);
            acc[nt] = __builtin_amdgcn_mfma_f32_16x16x32_f16(a, b, acc[nt], 0, 0, 0);
        }
    }
    // lane holds rows quad*4+r (r=0..3), cols nt*16+l16; head of col = nt>>2
    float asl[16], adl[16];
#pragma unroll
    for (int nt = 0; nt < 16; nt++) {
        asl[nt] = att_s[nt * 16 + l16];
        adl[nt] = att_d[nt * 16 + l16];
    }
    int orow0 = blockIdx.x * 64 + wave * 16 + quad * 4;
#pragma unroll
    for (int r = 0; r < 4; r++) {
        int orow = orow0 + r;
        float4 vs4, vd4;
        float* vsp = (float*)&vs4;
        float* vdp = (float*)&vd4;
#pragma unroll
        for (int hh = 0; hh < 4; hh++) {
            float vs = 0.f, vd = 0.f;
#pragma unroll
            for (int q = 0; q < 4; q++) {
                int nt = hh * 4 + q;
                float hv = acc[nt][r];
                vs += hv * asl[nt];
                vd += hv * adl[nt];
            }
            vs += __shfl_xor(vs, 1, 64); vd += __shfl_xor(vd, 1, 64);
            vs += __shfl_xor(vs, 2, 64); vd += __shfl_xor(vd, 2, 64);
            vs += __shfl_xor(vs, 4, 64); vd += __shfl_xor(vd, 4, 64);
            vs += __shfl_xor(vs, 8, 64); vd += __shfl_xor(vd, 8, 64);
            vsp[hh] = vs; vdp[hh] = vd;
        }
        if (l16 == 0 && orow < M) {
            ((float4*)asrc)[orow] = vs4;
            ((float4*)adst)[orow] = vd4;
        }
    }
#pragma unroll
    for (int r = 0; r < 4; r++) {
        int orow = orow0 + r;
        if (orow < M) {
#pragma unroll
            for (int nt = 0; nt < 16; nt++)
                H16[(size_t)orow * HC + nt * 16 + l16] = (_Float16)acc[nt][r];
        }
    }
}

// ---------------- we_att[d,h] = sum_c edgeW[d, h*64+c] * att_e[h,c] ----------------
__global__ void k_weatt(const float* __restrict__ edgeW, const float* __restrict__ att_e,
                        float* we) {
    int t = threadIdx.x;
    int d = t >> 2, hh = t & 3;
    float s = 0.f;
    for (int c = 0; c < 64; c++) s += edgeW[d * HC + hh * 64 + c] * att_e[hh * 64 + c];
    we[d * 4 + hh] = s;
}

// ---------------- elog{1,2}[pos(e),h] = edge_feat[e,:] . we{1,2}[:,h] ----------------
// One thread per edge, direct float4 global loads (ef is read exactly once -> no
// staging). we1/we2 (2 KB) live in LDS as conflict-free broadcast reads.
__global__ __launch_bounds__(256) void k_elog_both(const float* __restrict__ ef,
                                                   const float* __restrict__ we1,
                                                   const float* __restrict__ we2,
                                                   const int* __restrict__ epos,
                                                   float* __restrict__ elogc1,
                                                   float* __restrict__ elogc2, int E) {
    __shared__ float sw1[256], sw2[256];   // [c*4+head]
    int t = threadIdx.x;
    sw1[t] = we1[t];
    sw2[t] = we2[t];
    __syncthreads();
    int e = blockIdx.x * 256 + t;
    if (e >= E) return;
    int pos = epos[e];
    const float4* row = (const float4*)(ef + (size_t)e * EDIM);
    float a10 = 0.f, a11 = 0.f, a12 = 0.f, a13 = 0.f;
    float a20 = 0.f, a21 = 0.f, a22 = 0.f, a23 = 0.f;
#pragma unroll
    for (int c4 = 0; c4 < 16; c4++) {
        float4 v = row[c4];
        const float* vp = (const float*)&v;
#pragma unroll
        for (int k = 0; k < 4; k++) {
            float vv = vp[k];
            int c = c4 * 4 + k;
            float4 w1 = *(const float4*)&sw1[c << 2];
            float4 w2 = *(const float4*)&sw2[c << 2];
            a10 += vv * w1.x; a11 += vv * w1.y; a12 += vv * w1.z; a13 += vv * w1.w;
            a20 += vv * w2.x; a21 += vv * w2.y; a22 += vv * w2.z; a23 += vv * w2.w;
        }
    }
    ((float4*)elogc1)[pos] = make_float4(a10, a11, a12, a13);
    ((float4*)elogc2)[pos] = make_float4(a20, a21, a22, a23);
}

// ---------------- fused attention + aggregation, wave-cooperative ----------------
// wave per node. Per 64-edge chunk:
//  Phase A (edge-parallel): lane j loads srcs/elog/asrc of edge j (COALESCED),
//    computes all-4-head weights with __expf (4 exp per edge TOTAL), stores w4
//    to wave-private LDS; src id stays in a register.
//  Phase B (channel-parallel): per edge, readlane broadcasts src id to SGPR
//    (h-gather becomes saddr + constant lane voffset -> zero VALU addr math),
//    weight comes from a conflict-free LDS broadcast read.
template <int LAYER>
__global__ __launch_bounds__(256) void k_aggr_fused(const _Float16* __restrict__ hb,
                                                    const float* __restrict__ elogc,
                                                    const float* __restrict__ asrc,
                                                    const float* __restrict__ adst,
                                                    const int* __restrict__ offs,
                                                    const int* __restrict__ srcs,
                                                    const float* __restrict__ bias,
                                                    _Float16* __restrict__ out16,
                                                    float* __restrict__ out32, int N) {
    __shared__ float sW[4][256];   // [wave][edge*4+head]
    int wave = threadIdx.x >> 6, lane = threadIdx.x & 63;
    int n = blockIdx.x * 4 + wave;
    if (n >= N) return;
    int head = lane >> 4;
    const uint2* hf = (const uint2*)hb;     // 4 halves per entry, 64 entries per row
    const float4* elc = (const float4*)elogc;
    const float4* asp = (const float4*)asrc;
    float* sWp = sW[wave];
    int beg = offs[n], end = offs[n + 1];

    float4 adn = ((const float4*)adst)[n];
    float adnh = sel_h(adn, head);

    float denom = 0.f;
    float sx = 0.f, sy = 0.f, sz = 0.f, sw = 0.f;  // raw elog sums (all heads)
    float ax = 0.f, ay = 0.f, az = 0.f, aw = 0.f;

    for (int i0 = beg; i0 < end; i0 += 64) {
        int m = end - i0; if (m > 64) m = 64;
        bool act = lane < m;
        int sj = 0;
        float4 el = make_float4(0.f, 0.f, 0.f, 0.f);
        float4 a4 = make_float4(0.f, 0.f, 0.f, 0.f);
        if (act) {
            uint idx = (uint)(i0 + lane);
            sj = srcs[idx];
            el = elc[idx];
            a4 = asp[(uint)sj];
        }
        sx += el.x; sy += el.y; sz += el.z; sw += el.w;
        float4 w4;
        float l;
        l = a4.x + adn.x + el.x; l = l > 0.f ? l : 0.2f * l; w4.x = act ? __expf(l) : 0.f;
        l = a4.y + adn.y + el.y; l = l > 0.f ? l : 0.2f * l; w4.y = act ? __expf(l) : 0.f;
        l = a4.z + adn.z + el.z; l = l > 0.f ? l : 0.2f * l; w4.z = act ? __expf(l) : 0.f;
        l = a4.w + adn.w + el.w; l = l > 0.f ? l : 0.2f * l; w4.w = act ? __expf(l) : 0.f;
        *(float4*)&sWp[lane << 2] = w4;
        __builtin_amdgcn_wave_barrier();   // wave-private LDS; DS pipe is in-order per wave

        int j = 0;
        for (; j + 8 <= m; j += 8) {
            uint2 r[8];
            float w[8];
#pragma unroll
            for (int k = 0; k < 8; k++) {
                int sk = __builtin_amdgcn_readlane(sj, j + k);   // SGPR broadcast
                w[k] = sWp[((j + k) << 2) + head];
                r[k] = hf[(size_t)((uint)sk * 64u) + lane];
            }
#pragma unroll
            for (int k = 0; k < 8; k++) {
                float4 h4 = h4_to_f4(r[k]);
                denom += w[k];
                ax += w[k] * h4.x; ay += w[k] * h4.y;
                az += w[k] * h4.z; aw += w[k] * h4.w;
            }
        }
        for (; j < m; j++) {
            int sk = __builtin_amdgcn_readlane(sj, j);
            float wk = sWp[(j << 2) + head];
            uint2 rk = hf[(size_t)((uint)sk * 64u) + lane];
            float4 h4 = h4_to_f4(rk);
            denom += wk;
            ax += wk * h4.x; ay += wk * h4.y;
            az += wk * h4.z; aw += wk * h4.w;
        }
        __builtin_amdgcn_wave_barrier();   // before next chunk overwrites sW
    }

    // all-head elog totals (butterfly over 64 lanes), then pick own head
#pragma unroll
    for (int msk = 32; msk >= 1; msk >>= 1) {
        sx += __shfl_xor(sx, msk, 64);
        sy += __shfl_xor(sy, msk, 64);
        sz += __shfl_xor(sz, msk, 64);
        sw += __shfl_xor(sw, msk, 64);
    }
    float selh = sel_h(make_float4(sx, sy, sz, sw), head);

    // self-loop: attr = mean of incoming elog
    float cnt = (float)(end - beg);
    if (cnt < 1.f) cnt = 1.f;
    float asnh = sel_h(asp[(uint)n], head);
    float ls = asnh + adnh + selh / cnt;
    ls = ls > 0.f ? ls : 0.2f * ls;
    float ws = __expf(ls);
    denom += ws;
    float4 hn = h4_to_f4(hf[(size_t)n * 64 + lane]);
    ax += ws * hn.x; ay += ws * hn.y; az += ws * hn.z; aw += ws * hn.w;

    float inv = 1.0f / (denom + 1e-16f);
    ax *= inv; ay *= inv; az *= inv; aw *= inv;

    if (LAYER == 1) {
        float4 bv = ((const float4*)bias)[lane];
        half4v o;
        float v;
        v = ax + bv.x; o[0] = (_Float16)(v > 0.f ? v : __expf(v) - 1.0f);
        v = ay + bv.y; o[1] = (_Float16)(v > 0.f ? v : __expf(v) - 1.0f);
        v = az + bv.z; o[2] = (_Float16)(v > 0.f ? v : __expf(v) - 1.0f);
        v = aw + bv.w; o[3] = (_Float16)(v > 0.f ? v : __expf(v) - 1.0f);
        ((half4v*)(out16 + (size_t)n * HC))[lane] = o;
    } else {
        // mean over heads: reduce lanes {l, l^16, l^32, l^48}
        ax += __shfl_xor(ax, 16, 64); ax += __shfl_xor(ax, 32, 64);
        ay += __shfl_xor(ay, 16, 64); ay += __shfl_xor(ay, 32, 64);
        az += __shfl_xor(az, 16, 64); az += __shfl_xor(az, 32, 64);
        aw += __shfl_xor(aw, 16, 64); aw += __shfl_xor(aw, 32, 64);
        if (lane < 16) {
            float4 bv = ((const float4*)bias)[lane];
            float4 o;
            o.x = 0.25f * ax + bv.x;
            o.y = 0.25f * ay + bv.y;
            o.z = 0.25f * az + bv.z;
            o.w = 0.25f * aw + bv.w;
            ((float4*)(out32 + (size_t)n * CC))[lane] = o;
        }
    }
}

extern "C" void kernel_launch(void* const* d_in, const int* in_sizes, int n_in,
                              void* d_out, int out_size, void* d_ws, size_t ws_size,
                              hipStream_t stream) {
    const float* x   = (const float*)d_in[0];
    const float* ef  = (const float*)d_in[1];
    const int*   ei  = (const int*)d_in[2];
    const float* W1  = (const float*)d_in[3];
    const float* as1 = (const float*)d_in[4];
    const float* ad1 = (const float*)d_in[5];
    const float* ae1 = (const float*)d_in[6];
    const float* b1  = (const float*)d_in[7];
    const float* eW1 = (const float*)d_in[8];
    const float* W2  = (const float*)d_in[9];
    const float* as2 = (const float*)d_in[10];
    const float* ad2 = (const float*)d_in[11];
    const float* ae2 = (const float*)d_in[12];
    const float* b2  = (const float*)d_in[13];
    const float* eW2 = (const float*)d_in[14];
    float* out = (float*)d_out;
    const int* srcp = ei;
    const int* dstp = ei + NEDGE;

    char* w = (char*)d_ws;
    auto alloc = [&](size_t bytes) -> char* {
        char* r = w;
        w += (bytes + 255) / 256 * 256;
        return r;
    };
    _Float16* hb16  = (_Float16*)alloc((size_t)NNODE * HC * 2);   // h (fp16, both layers)
    _Float16* x216  = (_Float16*)alloc((size_t)NNODE * HC * 2);   // layer-2 GEMM input
    _Float16* wt1   = (_Float16*)alloc((size_t)HC * FIN * 2);     // W1^T fp16
    _Float16* wt2   = (_Float16*)alloc((size_t)HC * HC * 2);      // W2^T fp16
    float* elogc1 = (float*)alloc((size_t)NEDGE * 4 * 4);         // CSR-ordered
    float* elogc2 = (float*)alloc((size_t)NEDGE * 4 * 4);         // CSR-ordered
    float* asrc   = (float*)alloc((size_t)NNODE * 4 * 4);
    float* adst   = (float*)alloc((size_t)NNODE * 4 * 4);
    float* webuf1 = (float*)alloc(64 * 4 * 4);
    float* webuf2 = (float*)alloc(64 * 4 * 4);
    int* counts  = (int*)alloc((size_t)NNODE * 4);
    int* offs    = (int*)alloc((size_t)(NNODE + 1) * 4);
    int* tiles   = (int*)alloc(1024 * 4);
    int* cursor  = (int*)alloc((size_t)NNODE * 4);
    int* srcs    = (int*)alloc((size_t)NEDGE * 4);                // CSR-ordered src ids
    int* epos    = (int*)alloc((size_t)NEDGE * 4);                // edge -> CSR slot

    hipMemsetAsync(counts, 0, (size_t)NNODE * 4, stream);
    hipMemsetAsync(cursor, 0, (size_t)NNODE * 4, stream);

    // CSR build (shared by both layers)
    k_count<<<(NEDGE + 255) / 256, 256, 0, stream>>>(dstp, counts, NEDGE);
    int nt = (NNODE + SCAN_TILE - 1) / SCAN_TILE;
    k_scan1<<<nt, SCAN_TILE, 0, stream>>>(counts, offs, tiles, NNODE);
    k_scan2<<<1, 128, 0, stream>>>(tiles, nt);
    k_scan3<<<nt, SCAN_TILE, 0, stream>>>(offs, tiles, NNODE, NEDGE);
    k_fill<<<(NEDGE + 255) / 256, 256, 0, stream>>>(srcp, dstp, offs, cursor, srcs, epos, NEDGE);

    // fp16 weight transposes
    k_castW<<<FIN, 256, 0, stream>>>(W1, wt1, FIN);
    k_castW<<<HC, 256, 0, stream>>>(W2, wt2, HC);

    // edge logits for BOTH layers in one pass over ef, scattered to CSR order
    k_weatt<<<1, 256, 0, stream>>>(eW1, ae1, webuf1);
    k_weatt<<<1, 256, 0, stream>>>(eW2, ae2, webuf2);
    k_elog_both<<<(NEDGE + 255) / 256, 256, 0, stream>>>(ef, webuf1, webuf2, epos, elogc1, elogc2, NEDGE);

    // ---- layer 1 ----
    k_gemm_mfma<float><<<(NNODE + 63) / 64, 256, 0, stream>>>(x, wt1, hb16, as1, ad1, asrc, adst, NNODE, FIN);
    k_aggr_fused<1><<<(NNODE + 3) / 4, 256, 0, stream>>>(hb16, elogc1, asrc, adst, offs, srcs, b1, x216, nullptr, NNODE);

    // ---- layer 2 ----
    k_gemm_mfma<_Float16><<<(NNODE + 63) / 64, 256, 0, stream>>>(x216, wt2, hb16, as2, ad2, asrc, adst, NNODE, HC);
    k_aggr_fused<2><<<(NNODE + 3) / 4, 256, 0, stream>>>(hb16, elogc2, asrc, adst, offs, srcs, b2, nullptr, out, NNODE);
}

// Round 4
// 702.872 us; speedup vs baseline: 1.2530x; 1.0120x over previous
//
#include <hip/hip_runtime.h>
#include <hip/hip_fp16.h>
#include <math.h>

#define NNODE 50000
#define NEDGE 800000
#define FIN 128
#define EDIM 64
#define HC 256
#define NH 4
#define CC 64
#define SCAN_TILE 512

typedef _Float16 half8v __attribute__((ext_vector_type(8)));
typedef _Float16 half4v __attribute__((ext_vector_type(4)));
typedef float floatx4 __attribute__((ext_vector_type(4)));

// ---------------- fused setup: zero counts/cursor, cast W1/W2, we tables ----------------
// blocks [0,391): zero counts+cursor; [391,519): wt1; [519,775): wt2; [775,777): we1/we2
__global__ __launch_bounds__(256) void k_prep(int* counts, int* cursor,
                                              const float* __restrict__ W1, _Float16* wt1,
                                              const float* __restrict__ W2, _Float16* wt2,
                                              const float* __restrict__ eW1, const float* __restrict__ ae1, float* we1,
                                              const float* __restrict__ eW2, const float* __restrict__ ae2, float* we2) {
    int b = blockIdx.x, t = threadIdx.x;
    if (b < 391) {
        int i = b * 256 + t;
        if (i < NNODE) counts[i] = 0;
        else if (i < 2 * NNODE) cursor[i - NNODE] = 0;
    } else if (b < 519) {
        int idx = (b - 391) * 256 + t;          // 32768 = 256n x 128k
        int n = idx >> 7, k = idx & 127;
        wt1[n * FIN + k] = (_Float16)W1[(size_t)k * HC + n];
    } else if (b < 775) {
        int idx = (b - 519) * 256 + t;          // 65536 = 256n x 256k
        int n = idx >> 8, k = idx & 255;
        wt2[n * HC + k] = (_Float16)W2[(size_t)k * HC + n];
    } else {
        int idx = (b - 775) * 256 + t;          // 512: [0,256)->layer1, [256,512)->layer2
        const float* eW = idx < 256 ? eW1 : eW2;
        const float* ae = idx < 256 ? ae1 : ae2;
        float* we = idx < 256 ? we1 : we2;
        int q = idx & 255;
        int d = q >> 2, hh = q & 3;
        float s = 0.f;
        for (int c = 0; c < 64; c++) s += eW[d * HC + hh * 64 + c] * ae[hh * 64 + c];
        we[d * 4 + hh] = s;
    }
}

// ---------------- CSR build (dst -> incoming edge list) ----------------
__global__ void k_count(const int* __restrict__ dst, int* counts, int E) {
    int e = blockIdx.x * 256 + threadIdx.x;
    if (e < E) atomicAdd(&counts[dst[e]], 1);
}

__global__ void k_scan1(const int* __restrict__ counts, int* offs, int* tilesums, int N) {
    __shared__ int s[SCAN_TILE];
    int t = threadIdx.x;
    int i = blockIdx.x * SCAN_TILE + t;
    int v = (i < N) ? counts[i] : 0;
    s[t] = v;
    for (int off = 1; off < SCAN_TILE; off <<= 1) {
        __syncthreads();
        int x = (t >= off) ? s[t - off] : 0;
        __syncthreads();
        s[t] += x;
    }
    __syncthreads();
    if (i < N) offs[i] = s[t] - v;  // exclusive within tile
    if (t == SCAN_TILE - 1) tilesums[blockIdx.x] = s[t];
}

// parallel scan over tile sums (nt <= 128)
__global__ void k_scan2(int* tilesums, int nt) {
    __shared__ int s[128];
    int t = threadIdx.x;
    int v = (t < nt) ? tilesums[t] : 0;
    s[t] = v;
    for (int off = 1; off < 128; off <<= 1) {
        __syncthreads();
        int x = (t >= off) ? s[t - off] : 0;
        __syncthreads();
        s[t] += x;
    }
    __syncthreads();
    if (t < nt) tilesums[t] = s[t] - v;  // exclusive
}

__global__ void k_scan3(int* offs, const int* __restrict__ tilesums, int N, int E) {
    int t = threadIdx.x;
    int i = blockIdx.x * SCAN_TILE + t;
    if (i < N) offs[i] += tilesums[blockIdx.x];
    if (i == 0) offs[N] = E;
}

// es[pos] = {edge_id, src} -- single scattered 8B write
__global__ void k_fill(const int* __restrict__ src, const int* __restrict__ dst,
                       const int* __restrict__ offs, int* cursor,
                       int2* __restrict__ es, int E) {
    int e = blockIdx.x * 256 + threadIdx.x;
    if (e < E) {
        int d = dst[e];
        int pos = offs[d] + atomicAdd(&cursor[d], 1);
        es[pos] = make_int2(e, src[e]);
    }
}

__device__ inline float4 h4_to_f4(uint2 r) {
    float2 fa = __half22float2(*(__half2*)&r.x);
    float2 fb = __half22float2(*(__half2*)&r.y);
    return make_float4(fa.x, fa.y, fb.x, fb.y);
}

__device__ inline float sel_h(float4 v, int head) {
    return head == 0 ? v.x : head == 1 ? v.y : head == 2 ? v.z : v.w;
}

// ---------------- fp16 MFMA GEMM + fused avec epilogue ----------------
template <typename AT>
__global__ __launch_bounds__(256) void k_gemm_mfma(const AT* __restrict__ A,
                                                   const _Float16* __restrict__ Wt16,
                                                   _Float16* __restrict__ H16,
                                                   const float* __restrict__ att_s,
                                                   const float* __restrict__ att_d,
                                                   float* __restrict__ asrc,
                                                   float* __restrict__ adst,
                                                   int M, int K) {
    int wave = threadIdx.x >> 6, lane = threadIdx.x & 63;
    int quad = lane >> 4, l16 = lane & 15;
    int row = blockIdx.x * 64 + wave * 16 + l16;     // A-frag row (m = lane&15)
    bool rok = row < M;
    floatx4 acc[16];
#pragma unroll
    for (int i = 0; i < 16; i++) acc[i] = (floatx4)(0.0f);
    int nk = K >> 5;
    for (int kk = 0; kk < nk; kk++) {
        half8v a = {};
        if (rok) {
            if constexpr (sizeof(AT) == 2) {
                a = *(const half8v*)(A + (size_t)row * K + kk * 32 + quad * 8);
            } else {
                const float* ap = (const float*)A + (size_t)row * K + kk * 32 + quad * 8;
                float4 v0 = *(const float4*)ap;
                float4 v1 = *(const float4*)(ap + 4);
                a[0] = (_Float16)v0.x; a[1] = (_Float16)v0.y;
                a[2] = (_Float16)v0.z; a[3] = (_Float16)v0.w;
                a[4] = (_Float16)v1.x; a[5] = (_Float16)v1.y;
                a[6] = (_Float16)v1.z; a[7] = (_Float16)v1.w;
            }
        }
#pragma unroll
        for (int nt = 0; nt < 16; nt++) {
            half8v b = *(const half8v*)(Wt16 + (size_t)(nt * 16 + l16) * K + kk * 32 + quad * 8);
            acc[nt] = __builtin_amdgcn_mfma_f32_16x16x32_f16(a, b, acc[nt], 0, 0, 0);
        }
    }
    // lane holds rows quad*4+r (r=0..3), cols nt*16+l16; head of col = nt>>2
    float asl[16], adl[16];
#pragma unroll
    for (int nt = 0; nt < 16; nt++) {
        asl[nt] = att_s[nt * 16 + l16];
        adl[nt] = att_d[nt * 16 + l16];
    }
    int orow0 = blockIdx.x * 64 + wave * 16 + quad * 4;
#pragma unroll
    for (int r = 0; r < 4; r++) {
        int orow = orow0 + r;
        float4 vs4, vd4;
        float* vsp = (float*)&vs4;
        float* vdp = (float*)&vd4;
#pragma unroll
        for (int hh = 0; hh < 4; hh++) {
            float vs = 0.f, vd = 0.f;
#pragma unroll
            for (int q = 0; q < 4; q++) {
                int nt = hh * 4 + q;
                float hv = acc[nt][r];
                vs += hv * asl[nt];
                vd += hv * adl[nt];
            }
            vs += __shfl_xor(vs, 1, 64); vd += __shfl_xor(vd, 1, 64);
            vs += __shfl_xor(vs, 2, 64); vd += __shfl_xor(vd, 2, 64);
            vs += __shfl_xor(vs, 4, 64); vd += __shfl_xor(vd, 4, 64);
            vs += __shfl_xor(vs, 8, 64); vd += __shfl_xor(vd, 8, 64);
            vsp[hh] = vs; vdp[hh] = vd;
        }
        if (l16 == 0 && orow < M) {
            ((float4*)asrc)[orow] = vs4;
            ((float4*)adst)[orow] = vd4;
        }
    }
#pragma unroll
    for (int r = 0; r < 4; r++) {
        int orow = orow0 + r;
        if (orow < M) {
#pragma unroll
            for (int nt = 0; nt < 16; nt++)
                H16[(size_t)orow * HC + nt * 16 + l16] = (_Float16)acc[nt][r];
        }
    }
}

// ---------------- elog{1,2}[p,h] for CSR slot p = ef[es[p].x,:] . we{1,2}[:,h] ----------------
// CSR-ordered iteration: es read + elog writes fully coalesced; the ef row gather
// reads whole 256B rows (every byte consumed, L1 absorbs the 16-load burst).
__global__ __launch_bounds__(256) void k_elog_both(const float* __restrict__ ef,
                                                   const float* __restrict__ we1,
                                                   const float* __restrict__ we2,
                                                   const int2* __restrict__ es,
                                                   float* __restrict__ elogc1,
                                                   float* __restrict__ elogc2, int E) {
    __shared__ float sw1[256], sw2[256];   // [c*4+head]
    int t = threadIdx.x;
    sw1[t] = we1[t];
    sw2[t] = we2[t];
    __syncthreads();
    int p = blockIdx.x * 256 + t;
    if (p >= E) return;
    int e = es[p].x;
    const float4* row = (const float4*)(ef + (size_t)(uint)e * EDIM);
    float a10 = 0.f, a11 = 0.f, a12 = 0.f, a13 = 0.f;
    float a20 = 0.f, a21 = 0.f, a22 = 0.f, a23 = 0.f;
#pragma unroll
    for (int c4 = 0; c4 < 16; c4++) {
        float4 v = row[c4];
        const float* vp = (const float*)&v;
#pragma unroll
        for (int k = 0; k < 4; k++) {
            float vv = vp[k];
            int c = c4 * 4 + k;
            float4 w1 = *(const float4*)&sw1[c << 2];
            float4 w2 = *(const float4*)&sw2[c << 2];
            a10 += vv * w1.x; a11 += vv * w1.y; a12 += vv * w1.z; a13 += vv * w1.w;
            a20 += vv * w2.x; a21 += vv * w2.y; a22 += vv * w2.z; a23 += vv * w2.w;
        }
    }
    ((float4*)elogc1)[p] = make_float4(a10, a11, a12, a13);
    ((float4*)elogc2)[p] = make_float4(a20, a21, a22, a23);
}

// ---------------- fused attention + aggregation, wave-cooperative ----------------
// wave per node. Per 64-edge chunk:
//  Phase A (edge-parallel): lane j loads es/elog/asrc of edge j (COALESCED),
//    computes all-4-head weights with __expf, stores w4 to wave-private LDS.
//  Phase B (channel-parallel): per edge, readlane broadcasts src id to SGPR,
//    16 gathers kept in flight for MLP; weight via conflict-free LDS broadcast.
template <int LAYER>
__global__ __launch_bounds__(256) void k_aggr_fused(const _Float16* __restrict__ hb,
                                                    const float* __restrict__ elogc,
                                                    const float* __restrict__ asrc,
                                                    const float* __restrict__ adst,
                                                    const int* __restrict__ offs,
                                                    const int2* __restrict__ es,
                                                    const float* __restrict__ bias,
                                                    _Float16* __restrict__ out16,
                                                    float* __restrict__ out32, int N) {
    __shared__ float sW[4][256];   // [wave][edge*4+head]
    int wave = threadIdx.x >> 6, lane = threadIdx.x & 63;
    int n = blockIdx.x * 4 + wave;
    if (n >= N) return;
    int head = lane >> 4;
    const uint2* hf = (const uint2*)hb;     // 4 halves per entry, 64 entries per row
    const float4* elc = (const float4*)elogc;
    const float4* asp = (const float4*)asrc;
    float* sWp = sW[wave];
    int beg = offs[n], end = offs[n + 1];

    float4 adn = ((const float4*)adst)[n];
    float adnh = sel_h(adn, head);

    float denom = 0.f;
    float sx = 0.f, sy = 0.f, sz = 0.f, sw = 0.f;  // raw elog sums (all heads)
    float ax = 0.f, ay = 0.f, az = 0.f, aw = 0.f;

    for (int i0 = beg; i0 < end; i0 += 64) {
        int m = end - i0; if (m > 64) m = 64;
        bool act = lane < m;
        int sj = 0;
        float4 el = make_float4(0.f, 0.f, 0.f, 0.f);
        float4 a4 = make_float4(0.f, 0.f, 0.f, 0.f);
        if (act) {
            uint idx = (uint)(i0 + lane);
            sj = es[idx].y;
            el = elc[idx];
            a4 = asp[(uint)sj];
        }
        sx += el.x; sy += el.y; sz += el.z; sw += el.w;
        float4 w4;
        float l;
        l = a4.x + adn.x + el.x; l = l > 0.f ? l : 0.2f * l; w4.x = act ? __expf(l) : 0.f;
        l = a4.y + adn.y + el.y; l = l > 0.f ? l : 0.2f * l; w4.y = act ? __expf(l) : 0.f;
        l = a4.z + adn.z + el.z; l = l > 0.f ? l : 0.2f * l; w4.z = act ? __expf(l) : 0.f;
        l = a4.w + adn.w + el.w; l = l > 0.f ? l : 0.2f * l; w4.w = act ? __expf(l) : 0.f;
        *(float4*)&sWp[lane << 2] = w4;
        __builtin_amdgcn_wave_barrier();   // wave-private LDS; DS pipe is in-order per wave

        int j = 0;
        for (; j + 16 <= m; j += 16) {
            uint2 r[16];
            float w[16];
#pragma unroll
            for (int k = 0; k < 16; k++) {
                int sk = __builtin_amdgcn_readlane(sj, j + k);   // SGPR broadcast
                w[k] = sWp[((j + k) << 2) + head];
                r[k] = hf[(size_t)((uint)sk * 64u) + lane];
            }
#pragma unroll
            for (int k = 0; k < 16; k++) {
                float4 h4 = h4_to_f4(r[k]);
                denom += w[k];
                ax += w[k] * h4.x; ay += w[k] * h4.y;
                az += w[k] * h4.z; aw += w[k] * h4.w;
            }
        }
        for (; j + 8 <= m; j += 8) {
            uint2 r[8];
            float w[8];
#pragma unroll
            for (int k = 0; k < 8; k++) {
                int sk = __builtin_amdgcn_readlane(sj, j + k);
                w[k] = sWp[((j + k) << 2) + head];
                r[k] = hf[(size_t)((uint)sk * 64u) + lane];
            }
#pragma unroll
            for (int k = 0; k < 8; k++) {
                float4 h4 = h4_to_f4(r[k]);
                denom += w[k];
                ax += w[k] * h4.x; ay += w[k] * h4.y;
                az += w[k] * h4.z; aw += w[k] * h4.w;
            }
        }
        for (; j < m; j++) {
            int sk = __builtin_amdgcn_readlane(sj, j);
            float wk = sWp[(j << 2) + head];
            uint2 rk = hf[(size_t)((uint)sk * 64u) + lane];
            float4 h4 = h4_to_f4(rk);
            denom += wk;
            ax += wk * h4.x; ay += wk * h4.y;
            az += wk * h4.z; aw += wk * h4.w;
        }
        __builtin_amdgcn_wave_barrier();   // before next chunk overwrites sW
    }

    // all-head elog totals (butterfly over 64 lanes), then pick own head
#pragma unroll
    for (int msk = 32; msk >= 1; msk >>= 1) {
        sx += __shfl_xor(sx, msk, 64);
        sy += __shfl_xor(sy, msk, 64);
        sz += __shfl_xor(sz, msk, 64);
        sw += __shfl_xor(sw, msk, 64);
    }
    float selh = sel_h(make_float4(sx, sy, sz, sw), head);

    // self-loop: attr = mean of incoming elog
    float cnt = (float)(end - beg);
    if (cnt < 1.f) cnt = 1.f;
    float asnh = sel_h(asp[(uint)n], head);
    float ls = asnh + adnh + selh / cnt;
    ls = ls > 0.f ? ls : 0.2f * ls;
    float ws = __expf(ls);
    denom += ws;
    float4 hn = h4_to_f4(hf[(size_t)n * 64 + lane]);
    ax += ws * hn.x; ay += ws * hn.y; az += ws * hn.z; aw += ws * hn.w;

    float inv = 1.0f / (denom + 1e-16f);
    ax *= inv; ay *= inv; az *= inv; aw *= inv;

    if (LAYER == 1) {
        float4 bv = ((const float4*)bias)[lane];
        half4v o;
        float v;
        v = ax + bv.x; o[0] = (_Float16)(v > 0.f ? v : __expf(v) - 1.0f);
        v = ay + bv.y; o[1] = (_Float16)(v > 0.f ? v : __expf(v) - 1.0f);
        v = az + bv.z; o[2] = (_Float16)(v > 0.f ? v : __expf(v) - 1.0f);
        v = aw + bv.w; o[3] = (_Float16)(v > 0.f ? v : __expf(v) - 1.0f);
        ((half4v*)(out16 + (size_t)n * HC))[lane] = o;
    } else {
        // mean over heads: reduce lanes {l, l^16, l^32, l^48}
        ax += __shfl_xor(ax, 16, 64); ax += __shfl_xor(ax, 32, 64);
        ay += __shfl_xor(ay, 16, 64); ay += __shfl_xor(ay, 32, 64);
        az += __shfl_xor(az, 16, 64); az += __shfl_xor(az, 32, 64);
        aw += __shfl_xor(aw, 16, 64); aw += __shfl_xor(aw, 32, 64);
        if (lane < 16) {
            float4 bv = ((const float4*)bias)[lane];
            float4 o;
            o.x = 0.25f * ax + bv.x;
            o.y = 0.25f * ay + bv.y;
            o.z = 0.25f * az + bv.z;
            o.w = 0.25f * aw + bv.w;
            ((float4*)(out32 + (size_t)n * CC))[lane] = o;
        }
    }
}

extern "C" void kernel_launch(void* const* d_in, const int* in_sizes, int n_in,
                              void* d_out, int out_size, void* d_ws, size_t ws_size,
                              hipStream_t stream) {
    const float* x   = (const float*)d_in[0];
    const float* ef  = (const float*)d_in[1];
    const int*   ei  = (const int*)d_in[2];
    const float* W1  = (const float*)d_in[3];
    const float* as1 = (const float*)d_in[4];
    const float* ad1 = (const float*)d_in[5];
    const float* ae1 = (const float*)d_in[6];
    const float* b1  = (const float*)d_in[7];
    const float* eW1 = (const float*)d_in[8];
    const float* W2  = (const float*)d_in[9];
    const float* as2 = (const float*)d_in[10];
    const float* ad2 = (const float*)d_in[11];
    const float* ae2 = (const float*)d_in[12];
    const float* b2  = (const float*)d_in[13];
    const float* eW2 = (const float*)d_in[14];
    float* out = (float*)d_out;
    const int* srcp = ei;
    const int* dstp = ei + NEDGE;

    char* w = (char*)d_ws;
    auto alloc = [&](size_t bytes) -> char* {
        char* r = w;
        w += (bytes + 255) / 256 * 256;
        return r;
    };
    _Float16* hb16  = (_Float16*)alloc((size_t)NNODE * HC * 2);   // h (fp16, both layers)
    _Float16* x216  = (_Float16*)alloc((size_t)NNODE * HC * 2);   // layer-2 GEMM input
    _Float16* wt1   = (_Float16*)alloc((size_t)HC * FIN * 2);     // W1^T fp16
    _Float16* wt2   = (_Float16*)alloc((size_t)HC * HC * 2);      // W2^T fp16
    float* elogc1 = (float*)alloc((size_t)NEDGE * 4 * 4);         // CSR-ordered
    float* elogc2 = (float*)alloc((size_t)NEDGE * 4 * 4);         // CSR-ordered
    float* asrc   = (float*)alloc((size_t)NNODE * 4 * 4);
    float* adst   = (float*)alloc((size_t)NNODE * 4 * 4);
    float* webuf1 = (float*)alloc(64 * 4 * 4);
    float* webuf2 = (float*)alloc(64 * 4 * 4);
    int* counts  = (int*)alloc((size_t)NNODE * 4);
    int* offs    = (int*)alloc((size_t)(NNODE + 1) * 4);
    int* tiles   = (int*)alloc(1024 * 4);
    int* cursor  = (int*)alloc((size_t)NNODE * 4);
    int2* es     = (int2*)alloc((size_t)NEDGE * 8);               // {edge_id, src} CSR-ordered

    // fused setup (zeroing + weight transposes + we tables), one dispatch
    k_prep<<<777, 256, 0, stream>>>(counts, cursor, W1, wt1, W2, wt2,
                                    eW1, ae1, webuf1, eW2, ae2, webuf2);

    // CSR build (shared by both layers)
    k_count<<<(NEDGE + 255) / 256, 256, 0, stream>>>(dstp, counts, NEDGE);
    int nt = (NNODE + SCAN_TILE - 1) / SCAN_TILE;
    k_scan1<<<nt, SCAN_TILE, 0, stream>>>(counts, offs, tiles, NNODE);
    k_scan2<<<1, 128, 0, stream>>>(tiles, nt);
    k_scan3<<<nt, SCAN_TILE, 0, stream>>>(offs, tiles, NNODE, NEDGE);
    k_fill<<<(NEDGE + 255) / 256, 256, 0, stream>>>(srcp, dstp, offs, cursor, es, NEDGE);

    // edge logits for BOTH layers in one pass over ef, CSR-ordered (coalesced writes)
    k_elog_both<<<(NEDGE + 255) / 256, 256, 0, stream>>>(ef, webuf1, webuf2, es, elogc1, elogc2, NEDGE);

    // ---- layer 1 ----
    k_gemm_mfma<float><<<(NNODE + 63) / 64, 256, 0, stream>>>(x, wt1, hb16, as1, ad1, asrc, adst, NNODE, FIN);
    k_aggr_fused<1><<<(NNODE + 3) / 4, 256, 0, stream>>>(hb16, elogc1, asrc, adst, offs, es, b1, x216, nullptr, NNODE);

    // ---- layer 2 ----
    k_gemm_mfma<_Float16><<<(NNODE + 63) / 64, 256, 0, stream>>>(x216, wt2, hb16, as2, ad2, asrc, adst, NNODE, HC);
    k_aggr_fused<2><<<(NNODE + 3) / 4, 256, 0, stream>>>(hb16, elogc2, asrc, adst, offs, es, b2, nullptr, out, NNODE);
}

// Round 7
// 692.704 us; speedup vs baseline: 1.2714x; 1.0147x over previous
//
#include <hip/hip_runtime.h>
#include <hip/hip_fp16.h>
#include <math.h>

#define NNODE 50000
#define NEDGE 800000
#define FIN 128
#define EDIM 64
#define HC 256
#define NH 4
#define CC 64
#define SCAN_TILE 512

typedef _Float16 half8v __attribute__((ext_vector_type(8)));
typedef _Float16 half4v __attribute__((ext_vector_type(4)));
typedef float floatx4 __attribute__((ext_vector_type(4)));

// ---------------- fused setup: zero counts, cast W1/W2, we tables ----------------
// blocks [0,196): zero counts; [196,324): wt1; [324,580): wt2; [580,582): we1/we2
__global__ __launch_bounds__(256) void k_prep(int* counts,
                                              const float* __restrict__ W1, _Float16* wt1,
                                              const float* __restrict__ W2, _Float16* wt2,
                                              const float* __restrict__ eW1, const float* __restrict__ ae1, float* we1,
                                              const float* __restrict__ eW2, const float* __restrict__ ae2, float* we2) {
    int b = blockIdx.x, t = threadIdx.x;
    if (b < 196) {
        int i = b * 256 + t;
        if (i < NNODE) counts[i] = 0;
    } else if (b < 324) {
        int idx = (b - 196) * 256 + t;          // 32768 = 256n x 128k
        int n = idx >> 7, k = idx & 127;
        wt1[n * FIN + k] = (_Float16)W1[(size_t)k * HC + n];
    } else if (b < 580) {
        int idx = (b - 324) * 256 + t;          // 65536 = 256n x 256k
        int n = idx >> 8, k = idx & 255;
        wt2[n * HC + k] = (_Float16)W2[(size_t)k * HC + n];
    } else {
        int idx = (b - 580) * 256 + t;          // 512: [0,256)->layer1, [256,512)->layer2
        const float* eW = idx < 256 ? eW1 : eW2;
        const float* ae = idx < 256 ? ae1 : ae2;
        float* we = idx < 256 ? we1 : we2;
        int q = idx & 255;
        int d = q >> 2, hh = q & 3;
        float s = 0.f;
        for (int c = 0; c < 64; c++) s += eW[d * HC + hh * 64 + c] * ae[hh * 64 + c];
        we[d * 4 + hh] = s;
    }
}

// ---------------- count + rank (rank = arrival order within dst bucket) ----------------
__global__ void k_count(const int* __restrict__ dst, int* counts, int* __restrict__ rank, int E) {
    int e = blockIdx.x * 256 + threadIdx.x;
    if (e < E) rank[e] = atomicAdd(&counts[dst[e]], 1);
}

__global__ void k_scan1(const int* __restrict__ counts, int* offs, int* tilesums, int N) {
    __shared__ int s[SCAN_TILE];
    int t = threadIdx.x;
    int i = blockIdx.x * SCAN_TILE + t;
    int v = (i < N) ? counts[i] : 0;
    s[t] = v;
    for (int off = 1; off < SCAN_TILE; off <<= 1) {
        __syncthreads();
        int x = (t >= off) ? s[t - off] : 0;
        __syncthreads();
        s[t] += x;
    }
    __syncthreads();
    if (i < N) offs[i] = s[t] - v;  // exclusive within tile
    if (t == SCAN_TILE - 1) tilesums[blockIdx.x] = s[t];
}

// scan3 with fused tile-prefix: each block sums tilesums[0..b) from LDS
__global__ void k_scan3(int* offs, const int* __restrict__ tilesums, int nt, int N, int E) {
    __shared__ int sT[128];
    int t = threadIdx.x;
    if (t < 128) sT[t] = (t < nt) ? tilesums[t] : 0;
    __syncthreads();
    int b = blockIdx.x;
    int pre = 0;
    for (int i = 0; i < b; i++) pre += sT[i];   // uniform LDS broadcast loop
    int i = b * SCAN_TILE + t;
    if (i < N) offs[i] += pre;
    if (b == 0 && t == 0) offs[N] = E;
}

__device__ inline float4 h4_to_f4(uint2 r) {
    float2 fa = __half22float2(*(__half2*)&r.x);
    float2 fb = __half22float2(*(__half2*)&r.y);
    return make_float4(fa.x, fa.y, fb.x, fb.y);
}

__device__ inline float sel_h(float4 v, int head) {
    return head == 0 ? v.x : head == 1 ? v.y : head == 2 ? v.z : v.w;
}

// ---------------- fused CSR-fill + edge logits (single pass over edges) ----------------
// Edge-ordered: src/dst/rank and the 256B ef row are read SEQUENTIALLY; the
// CSR slot pos = offs[dst]+rank receives srcs (4B) + elogc1/2 (16B each) scattered
// (16B scattered writes showed no amplification in counters).
__global__ __launch_bounds__(256) void k_edge(const int* __restrict__ src,
                                              const int* __restrict__ dst,
                                              const int* __restrict__ rank,
                                              const int* __restrict__ offs,
                                              const float* __restrict__ ef,
                                              const float* __restrict__ we1,
                                              const float* __restrict__ we2,
                                              int* __restrict__ srcs,
                                              float* __restrict__ elogc1,
                                              float* __restrict__ elogc2, int E) {
    __shared__ float sw1[256], sw2[256];   // [c*4+head]
    int t = threadIdx.x;
    sw1[t] = we1[t];
    sw2[t] = we2[t];
    __syncthreads();
    int e = blockIdx.x * 256 + t;
    if (e >= E) return;
    int pos = offs[dst[e]] + rank[e];
    srcs[pos] = src[e];
    const float4* row = (const float4*)(ef + (size_t)e * EDIM);
    float a10 = 0.f, a11 = 0.f, a12 = 0.f, a13 = 0.f;
    float a20 = 0.f, a21 = 0.f, a22 = 0.f, a23 = 0.f;
#pragma unroll
    for (int c4 = 0; c4 < 16; c4++) {
        float4 v = row[c4];
        const float* vp = (const float*)&v;
#pragma unroll
        for (int k = 0; k < 4; k++) {
            float vv = vp[k];
            int c = c4 * 4 + k;
            float4 w1 = *(const float4*)&sw1[c << 2];
            float4 w2 = *(const float4*)&sw2[c << 2];
            a10 += vv * w1.x; a11 += vv * w1.y; a12 += vv * w1.z; a13 += vv * w1.w;
            a20 += vv * w2.x; a21 += vv * w2.y; a22 += vv * w2.z; a23 += vv * w2.w;
        }
    }
    ((float4*)elogc1)[pos] = make_float4(a10, a11, a12, a13);
    ((float4*)elogc2)[pos] = make_float4(a20, a21, a22, a23);
}

// ---------------- fp16 MFMA GEMM + fused avec epilogue ----------------
template <typename AT>
__global__ __launch_bounds__(256) void k_gemm_mfma(const AT* __restrict__ A,
                                                   const _Float16* __restrict__ Wt16,
                                                   _Float16* __restrict__ H16,
                                                   const float* __restrict__ att_s,
                                                   const float* __restrict__ att_d,
                                                   float* __restrict__ asrc,
                                                   float* __restrict__ adst,
                                                   int M, int K) {
    int wave = threadIdx.x >> 6, lane = threadIdx.x & 63;
    int quad = lane >> 4, l16 = lane & 15;
    int row = blockIdx.x * 64 + wave * 16 + l16;     // A-frag row (m = lane&15)
    bool rok = row < M;
    floatx4 acc[16];
#pragma unroll
    for (int i = 0; i < 16; i++) acc[i] = (floatx4)(0.0f);
    int nk = K >> 5;
    for (int kk = 0; kk < nk; kk++) {
        half8v a = {};
        if (rok) {
            if constexpr (sizeof(AT) == 2) {
                a = *(const half8v*)(A + (size_t)row * K + kk * 32 + quad * 8);
            } else {
                const float* ap = (const float*)A + (size_t)row * K + kk * 32 + quad * 8;
                float4 v0 = *(const float4*)ap;
                float4 v1 = *(const float4*)(ap + 4);
                a[0] = (_Float16)v0.x; a[1] = (_Float16)v0.y;
                a[2] = (_Float16)v0.z; a[3] = (_Float16)v0.w;
                a[4] = (_Float16)v1.x; a[5] = (_Float16)v1.y;
                a[6] = (_Float16)v1.z; a[7] = (_Float16)v1.w;
            }
        }
#pragma unroll
        for (int nt = 0; nt < 16; nt++) {
            half8v b = *(const half8v*)(Wt16 + (size_t)(nt * 16 + l16) * K + kk * 32 + quad * 8);
            acc[nt] = __builtin_amdgcn_mfma_f32_16x16x32_f16(a, b, acc[nt], 0, 0, 0);
        }
    }
    // lane holds rows quad*4+r (r=0..3), cols nt*16+l16; head of col = nt>>2
    float asl[16], adl[16];
#pragma unroll
    for (int nt = 0; nt < 16; nt++) {
        asl[nt] = att_s[nt * 16 + l16];
        adl[nt] = att_d[nt * 16 + l16];
    }
    int orow0 = blockIdx.x * 64 + wave * 16 + quad * 4;
#pragma unroll
    for (int r = 0; r < 4; r++) {
        int orow = orow0 + r;
        float4 vs4, vd4;
        float* vsp = (float*)&vs4;
        float* vdp = (float*)&vd4;
#pragma unroll
        for (int hh = 0; hh < 4; hh++) {
            float vs = 0.f, vd = 0.f;
#pragma unroll
            for (int q = 0; q < 4; q++) {
                int nt = hh * 4 + q;
                float hv = acc[nt][r];
                vs += hv * asl[nt];
                vd += hv * adl[nt];
            }
            vs += __shfl_xor(vs, 1, 64); vd += __shfl_xor(vd, 1, 64);
            vs += __shfl_xor(vs, 2, 64); vd += __shfl_xor(vd, 2, 64);
            vs += __shfl_xor(vs, 4, 64); vd += __shfl_xor(vd, 4, 64);
            vs += __shfl_xor(vs, 8, 64); vd += __shfl_xor(vd, 8, 64);
            vsp[hh] = vs; vdp[hh] = vd;
        }
        if (l16 == 0 && orow < M) {
            ((float4*)asrc)[orow] = vs4;
            ((float4*)adst)[orow] = vd4;
        }
    }
#pragma unroll
    for (int r = 0; r < 4; r++) {
        int orow = orow0 + r;
        if (orow < M) {
#pragma unroll
            for (int nt = 0; nt < 16; nt++)
                H16[(size_t)orow * HC + nt * 16 + l16] = (_Float16)acc[nt][r];
        }
    }
}

// ---------------- fused attention + aggregation, wave-cooperative ----------------
// wave per node. Per 64-edge chunk:
//  Phase A (edge-parallel): lane j loads srcs/elog/asrc of edge j (COALESCED),
//    computes all-4-head weights with __expf, stores w4 to wave-private LDS.
//  Phase B (channel-parallel): per edge, readlane broadcasts src id to SGPR,
//    16 gathers kept in flight for MLP; weight via conflict-free LDS broadcast.
template <int LAYER>
__global__ __launch_bounds__(256) void k_aggr_fused(const _Float16* __restrict__ hb,
                                                    const float* __restrict__ elogc,
                                                    const float* __restrict__ asrc,
                                                    const float* __restrict__ adst,
                                                    const int* __restrict__ offs,
                                                    const int* __restrict__ srcs,
                                                    const float* __restrict__ bias,
                                                    _Float16* __restrict__ out16,
                                                    float* __restrict__ out32, int N) {
    __shared__ float sW[4][256];   // [wave][edge*4+head]
    int wave = threadIdx.x >> 6, lane = threadIdx.x & 63;
    int n = blockIdx.x * 4 + wave;
    if (n >= N) return;
    int head = lane >> 4;
    const uint2* hf = (const uint2*)hb;     // 4 halves per entry, 64 entries per row
    const float4* elc = (const float4*)elogc;
    const float4* asp = (const float4*)asrc;
    float* sWp = sW[wave];
    int beg = offs[n], end = offs[n + 1];

    float4 adn = ((const float4*)adst)[n];
    float adnh = sel_h(adn, head);

    float denom = 0.f;
    float sx = 0.f, sy = 0.f, sz = 0.f, sw = 0.f;  // raw elog sums (all heads)
    float ax = 0.f, ay = 0.f, az = 0.f, aw = 0.f;

    for (int i0 = beg; i0 < end; i0 += 64) {
        int m = end - i0; if (m > 64) m = 64;
        bool act = lane < m;
        int sj = 0;
        float4 el = make_float4(0.f, 0.f, 0.f, 0.f);
        float4 a4 = make_float4(0.f, 0.f, 0.f, 0.f);
        if (act) {
            uint idx = (uint)(i0 + lane);
            sj = srcs[idx];
            el = elc[idx];
            a4 = asp[(uint)sj];
        }
        sx += el.x; sy += el.y; sz += el.z; sw += el.w;
        float4 w4;
        float l;
        l = a4.x + adn.x + el.x; l = l > 0.f ? l : 0.2f * l; w4.x = act ? __expf(l) : 0.f;
        l = a4.y + adn.y + el.y; l = l > 0.f ? l : 0.2f * l; w4.y = act ? __expf(l) : 0.f;
        l = a4.z + adn.z + el.z; l = l > 0.f ? l : 0.2f * l; w4.z = act ? __expf(l) : 0.f;
        l = a4.w + adn.w + el.w; l = l > 0.f ? l : 0.2f * l; w4.w = act ? __expf(l) : 0.f;
        *(float4*)&sWp[lane << 2] = w4;
        __builtin_amdgcn_wave_barrier();   // wave-private LDS; DS pipe is in-order per wave

        int j = 0;
        for (; j + 16 <= m; j += 16) {
            uint2 r[16];
            float w[16];
#pragma unroll
            for (int k = 0; k < 16; k++) {
                int sk = __builtin_amdgcn_readlane(sj, j + k);   // SGPR broadcast
                w[k] = sWp[((j + k) << 2) + head];
                r[k] = hf[(size_t)((uint)sk * 64u) + lane];
            }
#pragma unroll
            for (int k = 0; k < 16; k++) {
                float4 h4 = h4_to_f4(r[k]);
                denom += w[k];
                ax += w[k] * h4.x; ay += w[k] * h4.y;
                az += w[k] * h4.z; aw += w[k] * h4.w;
            }
        }
        for (; j + 8 <= m; j += 8) {
            uint2 r[8];
            float w[8];
#pragma unroll
            for (int k = 0; k < 8; k++) {
                int sk = __builtin_amdgcn_readlane(sj, j + k);
                w[k] = sWp[((j + k) << 2) + head];
                r[k] = hf[(size_t)((uint)sk * 64u) + lane];
            }
#pragma unroll
            for (int k = 0; k < 8; k++) {
                float4 h4 = h4_to_f4(r[k]);
                denom += w[k];
                ax += w[k] * h4.x; ay += w[k] * h4.y;
                az += w[k] * h4.z; aw += w[k] * h4.w;
            }
        }
        for (; j < m; j++) {
            int sk = __builtin_amdgcn_readlane(sj, j);
            float wk = sWp[(j << 2) + head];
            uint2 rk = hf[(size_t)((uint)sk * 64u) + lane];
            float4 h4 = h4_to_f4(rk);
            denom += wk;
            ax += wk * h4.x; ay += wk * h4.y;
            az += wk * h4.z; aw += wk * h4.w;
        }
        __builtin_amdgcn_wave_barrier();   // before next chunk overwrites sW
    }

    // all-head elog totals (butterfly over 64 lanes), then pick own head
#pragma unroll
    for (int msk = 32; msk >= 1; msk >>= 1) {
        sx += __shfl_xor(sx, msk, 64);
        sy += __shfl_xor(sy, msk, 64);
        sz += __shfl_xor(sz, msk, 64);
        sw += __shfl_xor(sw, msk, 64);
    }
    float selh = sel_h(make_float4(sx, sy, sz, sw), head);

    // self-loop: attr = mean of incoming elog
    float cnt = (float)(end - beg);
    if (cnt < 1.f) cnt = 1.f;
    float asnh = sel_h(asp[(uint)n], head);
    float ls = asnh + adnh + selh / cnt;
    ls = ls > 0.f ? ls : 0.2f * ls;
    float ws = __expf(ls);
    denom += ws;
    float4 hn = h4_to_f4(hf[(size_t)n * 64 + lane]);
    ax += ws * hn.x; ay += ws * hn.y; az += ws * hn.z; aw += ws * hn.w;

    float inv = 1.0f / (denom + 1e-16f);
    ax *= inv; ay *= inv; az *= inv; aw *= inv;

    if (LAYER == 1) {
        float4 bv = ((const float4*)bias)[lane];
        half4v o;
        float v;
        v = ax + bv.x; o[0] = (_Float16)(v > 0.f ? v : __expf(v) - 1.0f);
        v = ay + bv.y; o[1] = (_Float16)(v > 0.f ? v : __expf(v) - 1.0f);
        v = az + bv.z; o[2] = (_Float16)(v > 0.f ? v : __expf(v) - 1.0f);
        v = aw + bv.w; o[3] = (_Float16)(v > 0.f ? v : __expf(v) - 1.0f);
        ((half4v*)(out16 + (size_t)n * HC))[lane] = o;
    } else {
        // mean over heads: reduce lanes {l, l^16, l^32, l^48}
        ax += __shfl_xor(ax, 16, 64); ax += __shfl_xor(ax, 32, 64);
        ay += __shfl_xor(ay, 16, 64); ay += __shfl_xor(ay, 32, 64);
        az += __shfl_xor(az, 16, 64); az += __shfl_xor(az, 32, 64);
        aw += __shfl_xor(aw, 16, 64); aw += __shfl_xor(aw, 32, 64);
        if (lane < 16) {
            float4 bv = ((const float4*)bias)[lane];
            float4 o;
            o.x = 0.25f * ax + bv.x;
            o.y = 0.25f * ay + bv.y;
            o.z = 0.25f * az + bv.z;
            o.w = 0.25f * aw + bv.w;
            ((float4*)(out32 + (size_t)n * CC))[lane] = o;
        }
    }
}

extern "C" void kernel_launch(void* const* d_in, const int* in_sizes, int n_in,
                              void* d_out, int out_size, void* d_ws, size_t ws_size,
                              hipStream_t stream) {
    const float* x   = (const float*)d_in[0];
    const float* ef  = (const float*)d_in[1];
    const int*   ei  = (const int*)d_in[2];
    const float* W1  = (const float*)d_in[3];
    const float* as1 = (const float*)d_in[4];
    const float* ad1 = (const float*)d_in[5];
    const float* ae1 = (const float*)d_in[6];
    const float* b1  = (const float*)d_in[7];
    const float* eW1 = (const float*)d_in[8];
    const float* W2  = (const float*)d_in[9];
    const float* as2 = (const float*)d_in[10];
    const float* ad2 = (const float*)d_in[11];
    const float* ae2 = (const float*)d_in[12];
    const float* b2  = (const float*)d_in[13];
    const float* eW2 = (const float*)d_in[14];
    float* out = (float*)d_out;
    const int* srcp = ei;
    const int* dstp = ei + NEDGE;

    char* w = (char*)d_ws;
    auto alloc = [&](size_t bytes) -> char* {
        char* r = w;
        w += (bytes + 255) / 256 * 256;
        return r;
    };
    _Float16* hb16  = (_Float16*)alloc((size_t)NNODE * HC * 2);   // h (fp16, both layers)
    _Float16* x216  = (_Float16*)alloc((size_t)NNODE * HC * 2);   // layer-2 GEMM input
    _Float16* wt1   = (_Float16*)alloc((size_t)HC * FIN * 2);     // W1^T fp16
    _Float16* wt2   = (_Float16*)alloc((size_t)HC * HC * 2);      // W2^T fp16
    float* elogc1 = (float*)alloc((size_t)NEDGE * 4 * 4);         // CSR-ordered
    float* elogc2 = (float*)alloc((size_t)NEDGE * 4 * 4);         // CSR-ordered
    float* asrc   = (float*)alloc((size_t)NNODE * 4 * 4);
    float* adst   = (float*)alloc((size_t)NNODE * 4 * 4);
    float* webuf1 = (float*)alloc(64 * 4 * 4);
    float* webuf2 = (float*)alloc(64 * 4 * 4);
    int* counts  = (int*)alloc((size_t)NNODE * 4);
    int* offs    = (int*)alloc((size_t)(NNODE + 1) * 4);
    int* tiles   = (int*)alloc(1024 * 4);
    int* rank    = (int*)alloc((size_t)NEDGE * 4);                // arrival rank within dst
    int* srcs    = (int*)alloc((size_t)NEDGE * 4);                // CSR-ordered src ids

    // fused setup (counts zeroing + weight transposes + we tables), one dispatch
    k_prep<<<582, 256, 0, stream>>>(counts, W1, wt1, W2, wt2,
                                    eW1, ae1, webuf1, eW2, ae2, webuf2);

    // CSR build (shared by both layers); rank recorded during count
    k_count<<<(NEDGE + 255) / 256, 256, 0, stream>>>(dstp, counts, rank, NEDGE);
    int nt = (NNODE + SCAN_TILE - 1) / SCAN_TILE;
    k_scan1<<<nt, SCAN_TILE, 0, stream>>>(counts, offs, tiles, NNODE);
    k_scan3<<<nt, SCAN_TILE, 0, stream>>>(offs, tiles, nt, NNODE, NEDGE);

    // fused CSR-fill + edge logits: ONE pass over edges, sequential ef reads
    k_edge<<<(NEDGE + 255) / 256, 256, 0, stream>>>(srcp, dstp, rank, offs, ef,
                                                    webuf1, webuf2, srcs, elogc1, elogc2, NEDGE);

    // ---- layer 1 ----
    k_gemm_mfma<float><<<(NNODE + 63) / 64, 256, 0, stream>>>(x, wt1, hb16, as1, ad1, asrc, adst, NNODE, FIN);
    k_aggr_fused<1><<<(NNODE + 3) / 4, 256, 0, stream>>>(hb16, elogc1, asrc, adst, offs, srcs, b1, x216, nullptr, NNODE);

    // ---- layer 2 ----
    k_gemm_mfma<_Float16><<<(NNODE + 63) / 64, 256, 0, stream>>>(x216, wt2, hb16, as2, ad2, asrc, adst, NNODE, HC);
    k_aggr_fused<2><<<(NNODE + 3) / 4, 256, 0, stream>>>(hb16, elogc2, asrc, adst, offs, srcs, b2, nullptr, out, NNODE);
}